// Round 13
// baseline (322.436 us; speedup 1.0000x reference)
//
#include <hip/hip_runtime.h>

#define HWP 65536
#define NSP 1024
#define DCH 128
#define KC  64          // pooling k-chunks (rows per chunk = 1024)
#define JC  16          // m1 j-chunks (64 j's per chunk)

typedef float f32x4 __attribute__((ext_vector_type(4)));
typedef short bf16x8 __attribute__((ext_vector_type(8)));
typedef short bf16x4 __attribute__((ext_vector_type(4)));

__device__ __forceinline__ float lrelu(float v) { return v > 0.f ? v : 0.01f * v; }

__device__ __forceinline__ short f2bf(float f) {
    __bf16 h = (__bf16)f;
    return __builtin_bit_cast(short, h);
}

// raw barrier without the __syncthreads vmcnt(0) drain
__device__ __forceinline__ void raw_barrier() {
    asm volatile("s_barrier" ::: "memory");
}

// ---------------------------------------------------------------------------
// prep_w (verified)
// ---------------------------------------------------------------------------
__global__ __launch_bounds__(256) void prep_w(
    const float* __restrict__ w1, const float* __restrict__ b1,
    const float* __restrict__ bn0_g, const float* __restrict__ bn0_b,
    const float* __restrict__ w2, const float* __restrict__ b2,
    const float* __restrict__ bn1_g, const float* __restrict__ bn1_b,
    short* __restrict__ w1t, short* __restrict__ w2t,
    float* __restrict__ b1f, float* __restrict__ b2f)
{
    int t = blockIdx.x * 256 + threadIdx.x;
    if (t < 7 * 8 * 64 * 8) {
        int j = t & 7, lane = (t >> 3) & 63, nf = (t >> 9) & 7, ks = t >> 12;
        int ch = ks * 32 + (lane >> 4) * 8 + j;
        int d  = nf * 16 + (lane & 15);
        float v = (ch < 200) ? bn0_g[ch] * w1[ch * 128 + d] : 0.f;
        w1t[t] = f2bf(v);
    }
    if (t < 4 * 8 * 64 * 8) {
        int j = t & 7, lane = (t >> 3) & 63, nf = (t >> 9) & 7, ks = t >> 12;
        int k = ks * 32 + (lane >> 4) * 8 + j;
        int d = nf * 16 + (lane & 15);
        w2t[t] = f2bf(bn1_g[k] * w2[k * 128 + d]);
    }
    if (t < 128) {
        float s1 = b1[t], s2 = b2[t];
        for (int ch = 0; ch < 200; ++ch) s1 += bn0_b[ch] * w1[ch * 128 + t];
        for (int k = 0; k < 128; ++k)   s2 += bn1_b[k] * w2[k * 128 + t];
        b1f[t] = s1; b2f[t] = s2;
    }
}

// ---------------------------------------------------------------------------
// cnn_mfma (round-12 verified): 4 waves/block, xfT[d][pix] bf16
// ---------------------------------------------------------------------------
__global__ __launch_bounds__(256) void cnn_mfma(
    const float* __restrict__ x, const short* __restrict__ w1t,
    const float* __restrict__ b1f, const short* __restrict__ w2t,
    const float* __restrict__ b2f, short* __restrict__ xfT)
{
    __shared__ __align__(16) short a2[4][4][4][64][8];   // 64 KB
    const int t = threadIdx.x;
    const int w = t >> 6, l = t & 63;
    const int q = l >> 4, li = l & 15;
    const int pix0 = blockIdx.x * 256 + w * 64;

    f32x4 acc[4][8];
#pragma unroll
    for (int nf = 0; nf < 8; ++nf) {
        float bv = b1f[nf * 16 + li];
#pragma unroll
        for (int mf = 0; mf < 4; ++mf) acc[mf][nf] = (f32x4){bv, bv, bv, bv};
    }

    for (int ks = 0; ks < 7; ++ks) {
        bf16x8 a[4];
        if (ks < 6 || q == 0) {
            int k0 = ks * 32 + q * 8;
#pragma unroll
            for (int mf = 0; mf < 4; ++mf) {
                const float* sp = &x[(size_t)(pix0 + mf * 16 + li) * 200 + k0];
                float4 u = *(const float4*)sp;
                float4 v = *(const float4*)(sp + 4);
                a[mf][0] = f2bf(u.x); a[mf][1] = f2bf(u.y);
                a[mf][2] = f2bf(u.z); a[mf][3] = f2bf(u.w);
                a[mf][4] = f2bf(v.x); a[mf][5] = f2bf(v.y);
                a[mf][6] = f2bf(v.z); a[mf][7] = f2bf(v.w);
            }
        } else {
#pragma unroll
            for (int mf = 0; mf < 4; ++mf)
#pragma unroll
                for (int j = 0; j < 8; ++j) a[mf][j] = 0;
        }
#pragma unroll
        for (int nf = 0; nf < 8; ++nf) {
            bf16x8 b = *(const bf16x8*)&w1t[((ks * 8 + nf) * 64 + l) * 8];
#pragma unroll
            for (int mf = 0; mf < 4; ++mf)
                acc[mf][nf] = __builtin_amdgcn_mfma_f32_16x16x32_bf16(a[mf], b, acc[mf][nf], 0, 0, 0);
        }
    }

#pragma unroll
    for (int mf = 0; mf < 4; ++mf)
#pragma unroll
        for (int nf = 0; nf < 8; ++nf)
#pragma unroll
            for (int j = 0; j < 4; ++j) {
                float v = lrelu(acc[mf][nf][j]);
                int row = mf * 16 + q * 4 + j;
                int col = nf * 16 + li;
                int ks2 = col >> 5;
                int lane2 = (row & 15) + (((col & 31) >> 3) << 4);
                a2[w][ks2][mf][lane2][col & 7] = f2bf(v);
            }
    __syncthreads();

    f32x4 acc2[4][8];
#pragma unroll
    for (int nf = 0; nf < 8; ++nf) {
        float bv = b2f[nf * 16 + li];
#pragma unroll
        for (int mf = 0; mf < 4; ++mf) acc2[mf][nf] = (f32x4){bv, bv, bv, bv};
    }
#pragma unroll
    for (int ks = 0; ks < 4; ++ks) {
        bf16x8 a[4];
#pragma unroll
        for (int mf = 0; mf < 4; ++mf)
            a[mf] = *(const bf16x8*)&a2[w][ks][mf][l][0];
#pragma unroll
        for (int nf = 0; nf < 8; ++nf) {
            bf16x8 b = *(const bf16x8*)&w2t[((ks * 8 + nf) * 64 + l) * 8];
#pragma unroll
            for (int mf = 0; mf < 4; ++mf)
                acc2[mf][nf] = __builtin_amdgcn_mfma_f32_16x16x32_bf16(a[mf], b, acc2[mf][nf], 0, 0, 0);
        }
    }

#pragma unroll
    for (int mf = 0; mf < 4; ++mf)
#pragma unroll
        for (int nf = 0; nf < 8; ++nf) {
            bf16x4 p;
#pragma unroll
            for (int j = 0; j < 4; ++j) p[j] = f2bf(lrelu(acc2[mf][nf][j]));
            int d2 = nf * 16 + li;
            int pix = pix0 + mf * 16 + q * 4;
            *(bf16x4*)&xfT[(size_t)d2 * HWP + pix] = p;
        }
}

// ---------------------------------------------------------------------------
// pool_mfma: 8-wave (512-thread) blocks, same 128n x 128d x 1024r tile.
// Waves: dh = wid&1 (d-half), nq = wid>>1 (n-quarter, 32 n each).
// Q tile [64r][128n] fp32 = 32KB x2; 12 vmem ops in flight/tile -> vmcnt(12).
// ---------------------------------------------------------------------------
__device__ __forceinline__ void pool_loadB(bf16x8 (&dst)[4], const short* __restrict__ xfT,
                                           int dcol0, int rbase)
{
#pragma unroll
    for (int nf = 0; nf < 4; ++nf)
        dst[nf] = *(const bf16x8*)&xfT[(size_t)(dcol0 + nf * 16) * HWP + rbase];
}

__device__ __forceinline__ void pool_stage(const float* __restrict__ Q, float* dst,
                                           int r0t, int n0blk, int wid, int l)
{
#pragma unroll
    for (int i = 0; i < 4; ++i) {
        int o = (i * 8 + wid) * 1024 + l * 16;     // byte offset in 32KB tile
        int row = o >> 9;                          // 512B per row (128 fp32)
        int wrd = (o & 511) >> 2;                  // word-in-row 0..127
        const float* src = Q + (size_t)(r0t + row) * NSP + n0blk
                             + (wrd ^ (((row >> 3) & 3) << 4));
        __builtin_amdgcn_global_load_lds(
            (const __attribute__((address_space(1))) unsigned int*)src,
            (__attribute__((address_space(3))) unsigned int*)(dst + (o >> 2)),
            16, 0, 0);
    }
}

__global__ __launch_bounds__(512, 4) void pool_mfma(
    const float* __restrict__ Q, const short* __restrict__ xfT,
    float* __restrict__ P_part, float* __restrict__ qs_part)
{
    __shared__ __align__(16) float qtile[2][8192];   // 2 x 32KB
    const int t = threadIdx.x;
    const int wid = t >> 6, l = t & 63;
    const int q = l >> 4, li = l & 15;
    const int nw = (wid >> 1) * 32;                  // wave n-quarter
    const int d0 = (wid & 1) * 64;
    const int n0blk = blockIdx.x * 128;
    const int chunk = blockIdx.y;
    const int r0 = chunk * 1024;
    const int dcol0 = d0 + li;

    f32x4 acc[2][4];
    f32x4 accq[2];
#pragma unroll
    for (int mf = 0; mf < 2; ++mf) {
        accq[mf] = (f32x4){0.f, 0.f, 0.f, 0.f};
#pragma unroll
        for (int nf = 0; nf < 4; ++nf) acc[mf][nf] = (f32x4){0.f, 0.f, 0.f, 0.f};
    }
    bf16x8 bone;
    {
        short onev = (li == 0) ? (short)0x3F80 : (short)0;
#pragma unroll
        for (int j = 0; j < 8; ++j) bone[j] = onev;
    }

    // prologue: B(t0) (8 ops) + stage(t0) (4 ops) = 12 in flight
    bf16x8 bA[4], bB[4];
    pool_loadB(bA, xfT, dcol0, r0 + q * 8);
    pool_loadB(bB, xfT, dcol0, r0 + 32 + q * 8);
    pool_stage(Q, qtile[0], r0, n0blk, wid, l);

    for (int tile = 0; tile < 16; ++tile) {
        const int cur = tile & 1;
        raw_barrier();                               // prev compute's reads done
        bf16x8 nA[4], nB[4];
        if (tile < 15) {
            pool_loadB(nA, xfT, dcol0, r0 + (tile + 1) * 64 + q * 8);
            pool_loadB(nB, xfT, dcol0, r0 + (tile + 1) * 64 + 32 + q * 8);
            pool_stage(Q, qtile[cur ^ 1], r0 + (tile + 1) * 64, n0blk, wid, l);
            asm volatile("s_waitcnt vmcnt(12)" ::: "memory");   // tile-t's 12 done
        } else {
            asm volatile("s_waitcnt vmcnt(0)" ::: "memory");
        }
        raw_barrier();                               // stage(tile) visible
        __builtin_amdgcn_sched_barrier(0);
#pragma unroll
        for (int ks = 0; ks < 2; ++ks) {
            bf16x8 abf[2];
#pragma unroll
            for (int mf = 0; mf < 2; ++mf) {
#pragma unroll
                for (int j = 0; j < 8; ++j) {
                    int row = ks * 32 + q * 8 + j;           // (row>>3)&3 == q
                    int w2i = (nw + mf * 16 + li) ^ (q << 4);
                    abf[mf][j] = f2bf(qtile[cur][(row << 7) + w2i]);
                }
            }
#pragma unroll
            for (int mf = 0; mf < 2; ++mf) {
#pragma unroll
                for (int nf = 0; nf < 4; ++nf)
                    acc[mf][nf] = __builtin_amdgcn_mfma_f32_16x16x32_bf16(
                        abf[mf], (ks == 0) ? bA[nf] : bB[nf], acc[mf][nf], 0, 0, 0);
                if (d0 == 0)
                    accq[mf] = __builtin_amdgcn_mfma_f32_16x16x32_bf16(
                        abf[mf], bone, accq[mf], 0, 0, 0);
            }
        }
        if (tile < 15) {
#pragma unroll
            for (int nf = 0; nf < 4; ++nf) { bA[nf] = nA[nf]; bB[nf] = nB[nf]; }
        }
    }

#pragma unroll
    for (int mf = 0; mf < 2; ++mf)
#pragma unroll
        for (int nf = 0; nf < 4; ++nf)
#pragma unroll
            for (int j = 0; j < 4; ++j) {
                int n = n0blk + nw + mf * 16 + q * 4 + j;
                int d = d0 + nf * 16 + li;
                P_part[((size_t)chunk * NSP + n) * DCH + d] = acc[mf][nf][j];
            }
    if (d0 == 0 && li == 0)
#pragma unroll
        for (int mf = 0; mf < 2; ++mf)
#pragma unroll
            for (int j = 0; j < 4; ++j)
                qs_part[chunk * NSP + n0blk + nw + mf * 16 + q * 4 + j] = accq[mf][j];
}

// ---------------------------------------------------------------------------
__global__ __launch_bounds__(256) void reduce_h0(
    const float* __restrict__ P_part, const float* __restrict__ qs_part,
    float* __restrict__ h)
{
    const int i4 = blockIdx.x * 256 + threadIdx.x;
    const int n = i4 >> 5;
    f32x4 s = (f32x4){0.f, 0.f, 0.f, 0.f};
    const f32x4* P4 = (const f32x4*)P_part;
    for (int k = 0; k < KC; ++k) s += P4[(size_t)k * (NSP * DCH / 4) + i4];
    float qs = 0.f;
    for (int k = 0; k < KC; ++k) qs += qs_part[k * NSP + n];
    float inv = 1.f / qs;
    ((f32x4*)h)[i4] = s * inv;
}

// ---------------------------------------------------------------------------
__global__ __launch_bounds__(256) void dinv_k(const float* __restrict__ adj,
                                              float* __restrict__ dinv)
{
    __shared__ float red[256];
    const int n = blockIdx.x;
    const int t = threadIdx.x;
    float4 v = *(const float4*)&adj[(size_t)n * NSP + t * 4];
    red[t] = v.x + v.y + v.z + v.w;
    __syncthreads();
    for (int off = 128; off > 0; off >>= 1) {
        if (t < off) red[t] += red[t + off];
        __syncthreads();
    }
    if (t == 0) dinv[n] = rsqrtf(red[0] + 1.0f);
}

// ---------------------------------------------------------------------------
// m1_k (verified): grid (64 r-tiles, 16 j-chunks of 64)
// ---------------------------------------------------------------------------
__global__ __launch_bounds__(256) void m1_k(
    const float* __restrict__ adj, const float* __restrict__ h,
    const float* __restrict__ dinv, const float* __restrict__ gg,
    const float* __restrict__ gb, float* __restrict__ m1p)
{
    __shared__ float adjL[16][64];
    __shared__ float hbL[64][128];
    const int r0 = blockIdx.x * 16;
    const int jc = blockIdx.y;
    const int j0 = jc * 64;
    const int t = threadIdx.x;
    const int d = t & 127, ph = t >> 7;

    for (int i = t; i < 16 * 64; i += 256) {
        int row = i >> 6, col = i & 63;
        adjL[row][col] = adj[(size_t)(r0 + row) * NSP + j0 + col];
    }
    for (int i = t; i < 64 * 128; i += 256) {
        int jr = i >> 7, dd = i & 127;
        int j = j0 + jr;
        hbL[jr][dd] = dinv[j] * (gg[dd] * h[(size_t)j * DCH + dd] + gb[dd]);
    }
    __syncthreads();

    float acc[8];
#pragma unroll
    for (int pp = 0; pp < 8; ++pp) acc[pp] = 0.f;
    for (int jj = 0; jj < 64; ++jj) {
        float hv = hbL[jj][d];
#pragma unroll
        for (int pp = 0; pp < 8; ++pp)
            acc[pp] += adjL[ph * 8 + pp][jj] * hv;
    }
#pragma unroll
    for (int pp = 0; pp < 8; ++pp)
        m1p[(size_t)jc * (NSP * DCH) + (size_t)(r0 + ph * 8 + pp) * DCH + d] = acc[pp];
}

// ---------------------------------------------------------------------------
// gcnw_k (verified) + fused htb write
// ---------------------------------------------------------------------------
__global__ __launch_bounds__(256) void gcnw_k(
    const float* __restrict__ m1p, const float* __restrict__ h,
    const float* __restrict__ dinv, const float* __restrict__ gg,
    const float* __restrict__ gb, const float* __restrict__ W,
    const float* __restrict__ bias, float* __restrict__ hout,
    short* __restrict__ htb)
{
    __shared__ float ms[16 * 128];
    __shared__ float WL[64 * 128];
    const int r0 = blockIdx.x * 16;
    const int t = threadIdx.x;
    for (int i = t; i < 2048; i += 256) {
        int r = r0 + (i >> 7), dd = i & 127;
        float hbr = dinv[r] * (gg[dd] * h[(size_t)r * DCH + dd] + gb[dd]);
        float s = hbr;
#pragma unroll
        for (int kc = 0; kc < JC; ++kc)
            s += m1p[(size_t)kc * (NSP * DCH) + (size_t)r0 * DCH + i];
        ms[i] = dinv[r] * s;
    }
    const int e = t & 127, ph = t >> 7;
    float acc[8];
#pragma unroll
    for (int pp = 0; pp < 8; ++pp) acc[pp] = bias[e];
    for (int sub = 0; sub < 2; ++sub) {
        __syncthreads();
        for (int i = t; i < 64 * 128; i += 256)
            WL[i] = W[(size_t)sub * 64 * 128 + i];
        __syncthreads();
        for (int dd = 0; dd < 64; ++dd) {
            float wv = WL[dd * 128 + e];
#pragma unroll
            for (int pp = 0; pp < 8; ++pp)
                acc[pp] += ms[(ph * 8 + pp) * 128 + sub * 64 + dd] * wv;
        }
    }
#pragma unroll
    for (int pp = 0; pp < 8; ++pp) {
        int r = r0 + ph * 8 + pp;
        float v = lrelu(acc[pp]);
        hout[(size_t)r * DCH + e] = v;
        int lane = (((r >> 3) & 3) << 4) + (e & 15);
        htb[(((r >> 5) * 8 + (e >> 4)) * 64 + lane) * 8 + (r & 7)] = f2bf(v);
    }
}

// ---------------------------------------------------------------------------
// out_mfma: 8-wave (512-thread) blocks, same 128r x 128d tile, K=1024.
// Waves: rh = wid>>1 (row-quarter, 32 r each), dh = wid&1.
// Q tile [128r][64k] fp32 = 32KB x2; 12 vmem ops/tile -> vmcnt(12).
// ---------------------------------------------------------------------------
__device__ __forceinline__ void out_loadB(bf16x8 (&dst)[4], const short* __restrict__ htb,
                                          int ks, int nfbase, int l)
{
#pragma unroll
    for (int nf = 0; nf < 4; ++nf)
        dst[nf] = *(const bf16x8*)&htb[((ks * 8 + nfbase + nf) * 64 + l) * 8];
}

__device__ __forceinline__ void stage_q(const float* __restrict__ Q, float* dst,
                                        int r0, int kbase, int wid, int l)
{
#pragma unroll
    for (int i = 0; i < 4; ++i) {
        int o = (i * 8 + wid) * 1024 + l * 16;      // byte offset in 32KB tile
        int row = o >> 8;                           // 256B per row (64 fp32)
        int bin = o & 255;                          // 16B-aligned
        const float* src = Q + (size_t)(r0 + row) * NSP + kbase
                             + ((bin ^ ((row & 7) << 5)) >> 2);
        __builtin_amdgcn_global_load_lds(
            (const __attribute__((address_space(1))) unsigned int*)src,
            (__attribute__((address_space(3))) unsigned int*)(dst + (o >> 2)),
            16, 0, 0);
    }
}

__global__ __launch_bounds__(512, 4) void out_mfma(
    const float* __restrict__ Q, const short* __restrict__ htb,
    float* __restrict__ out)
{
    __shared__ __align__(16) float qs[2][8192];     // 2 x 32KB
    const int t = threadIdx.x;
    const int wid = t >> 6, l = t & 63;
    const int q = l >> 4, li = l & 15;
    const int r0 = blockIdx.x * 128;
    const int rw = (wid >> 1) * 32;                 // wave's row-quarter
    const int d0 = (wid & 1) * 64;
    const int nfb = d0 >> 4;

    f32x4 acc[2][4];
#pragma unroll
    for (int mf = 0; mf < 2; ++mf)
#pragma unroll
        for (int nf = 0; nf < 4; ++nf) acc[mf][nf] = (f32x4){0.f, 0.f, 0.f, 0.f};

    bf16x8 bA[4], bB[4];
    out_loadB(bA, htb, 0, nfb, l);
    out_loadB(bB, htb, 1, nfb, l);
    stage_q(Q, qs[0], r0, 0, wid, l);

    for (int tile = 0; tile < 16; ++tile) {
        const int cur = tile & 1;
        raw_barrier();                               // prev compute's reads done
        bf16x8 nA[4], nB[4];
        if (tile < 15) {
            out_loadB(nA, htb, (tile + 1) * 2,     nfb, l);
            out_loadB(nB, htb, (tile + 1) * 2 + 1, nfb, l);
            stage_q(Q, qs[cur ^ 1], r0, (tile + 1) * 64, wid, l);
            asm volatile("s_waitcnt vmcnt(12)" ::: "memory");
        } else {
            asm volatile("s_waitcnt vmcnt(0)" ::: "memory");
        }
        raw_barrier();                               // stage(tile) visible
        __builtin_amdgcn_sched_barrier(0);
#pragma unroll
        for (int ks = 0; ks < 2; ++ks) {
            bf16x8 abf[2];
#pragma unroll
            for (int mf = 0; mf < 2; ++mf) {
                int rl = rw + mf * 16 + li;
                int koff = (ks * 32 + q * 8) << 2;
                const float* p = &qs[cur][(rl << 6) + ((koff ^ ((rl & 7) << 5)) >> 2)];
                float4 u = *(const float4*)p;
                float4 v = *(const float4*)(p + 4);
                abf[mf][0] = f2bf(u.x); abf[mf][1] = f2bf(u.y);
                abf[mf][2] = f2bf(u.z); abf[mf][3] = f2bf(u.w);
                abf[mf][4] = f2bf(v.x); abf[mf][5] = f2bf(v.y);
                abf[mf][6] = f2bf(v.z); abf[mf][7] = f2bf(v.w);
            }
            if (ks == 0) {
#pragma unroll
                for (int mf = 0; mf < 2; ++mf)
#pragma unroll
                    for (int nf = 0; nf < 4; ++nf)
                        acc[mf][nf] = __builtin_amdgcn_mfma_f32_16x16x32_bf16(abf[mf], bA[nf], acc[mf][nf], 0, 0, 0);
            } else {
#pragma unroll
                for (int mf = 0; mf < 2; ++mf)
#pragma unroll
                    for (int nf = 0; nf < 4; ++nf)
                        acc[mf][nf] = __builtin_amdgcn_mfma_f32_16x16x32_bf16(abf[mf], bB[nf], acc[mf][nf], 0, 0, 0);
            }
        }
        if (tile < 15) {
#pragma unroll
            for (int nf = 0; nf < 4; ++nf) { bA[nf] = nA[nf]; bB[nf] = nB[nf]; }
        }
    }

#pragma unroll
    for (int mf = 0; mf < 2; ++mf)
#pragma unroll
        for (int nf = 0; nf < 4; ++nf)
#pragma unroll
            for (int j = 0; j < 4; ++j)
                out[(size_t)(r0 + rw + mf * 16 + q * 4 + j) * DCH + d0 + nf * 16 + li] = acc[mf][nf][j];
}

// ---------------------------------------------------------------------------
extern "C" void kernel_launch(void* const* d_in, const int* in_sizes, int n_in,
                              void* d_out, int out_size, void* d_ws, size_t ws_size,
                              hipStream_t stream)
{
    const float* x      = (const float*)d_in[0];
    const float* Q      = (const float*)d_in[1];
    const float* adj    = (const float*)d_in[2];
    const float* bn0_g  = (const float*)d_in[3];
    const float* bn0_b  = (const float*)d_in[4];
    const float* w1     = (const float*)d_in[5];
    const float* b1     = (const float*)d_in[6];
    const float* bn1_g  = (const float*)d_in[7];
    const float* bn1_b  = (const float*)d_in[8];
    const float* w2     = (const float*)d_in[9];
    const float* b2     = (const float*)d_in[10];
    const float* gbn_g  = (const float*)d_in[11];
    const float* gbn_b  = (const float*)d_in[12];
    const float* gcn_w  = (const float*)d_in[13];
    const float* gcn_b  = (const float*)d_in[14];

    float* out = (float*)d_out;
    float* ws  = (float*)d_ws;

    // workspace layout (float units)
    float* P_part  = ws;                                   // 8,388,608
    float* qs_part = P_part + (size_t)KC * NSP * DCH;      // 65,536
    float* hA      = qs_part + (size_t)KC * NSP;           // 131,072
    float* hB      = hA + NSP * DCH;                       // 131,072
    float* dinvb   = hB + NSP * DCH;                       // 1,024
    short* htb     = (short*)(dinvb + NSP);                // 131,072 bf16
    short* w1t     = (short*)((float*)htb + 65536);        // 28,672 bf16
    short* w2t     = (short*)((float*)w1t + 14336);        // 16,384 bf16
    float* b1f     = (float*)w2t + 8192;                   // 128
    float* b2f     = b1f + 128;                            // 128
    // GCN partials overlay P_part (dead after reduce_h0)
    float* m1p     = P_part;
    // xfT lives in the (currently dead) d_out buffer
    short* xfT     = (short*)d_out;

    prep_w<<<112, 256, 0, stream>>>(w1, b1, bn0_g, bn0_b, w2, b2, bn1_g, bn1_b,
                                    w1t, w2t, b1f, b2f);
    cnn_mfma<<<HWP / 256, 256, 0, stream>>>(x, w1t, b1f, w2t, b2f, xfT);
    pool_mfma<<<dim3(NSP / 128, KC), 512, 0, stream>>>(Q, xfT, P_part, qs_part);
    reduce_h0<<<(NSP * DCH / 4) / 256, 256, 0, stream>>>(P_part, qs_part, hA);
    dinv_k<<<NSP, 256, 0, stream>>>(adj, dinvb);

    const float* hcur = hA;
    float* hnext = hB;
    for (int i = 0; i < 3; ++i) {
        m1_k<<<dim3(NSP / 16, JC), 256, 0, stream>>>(adj, hcur, dinvb,
                                                     gbn_g + i * DCH, gbn_b + i * DCH, m1p);
        gcnw_k<<<NSP / 16, 256, 0, stream>>>(m1p, hcur, dinvb,
                                             gbn_g + i * DCH, gbn_b + i * DCH,
                                             gcn_w + (size_t)i * DCH * DCH,
                                             gcn_b + i * DCH, hnext, htb);
        const float* tmp = hcur;
        hcur = hnext;
        hnext = (float*)tmp;
    }

    out_mfma<<<HWP / 128, 512, 0, stream>>>(Q, htb, out);
}

// Round 14
// 270.759 us; speedup vs baseline: 1.1909x; 1.1909x over previous
//
#include <hip/hip_runtime.h>

#define HWP 65536
#define NSP 1024
#define DCH 128
#define KC  64          // pooling k-chunks (rows per chunk = 1024)
#define JC  16          // m1 j-chunks (64 j's per chunk)

typedef float f32x4 __attribute__((ext_vector_type(4)));
typedef short bf16x8 __attribute__((ext_vector_type(8)));
typedef short bf16x4 __attribute__((ext_vector_type(4)));

__device__ __forceinline__ float lrelu(float v) { return v > 0.f ? v : 0.01f * v; }

// native conversion -> compiler emits v_cvt_pk_bf16_f32 pairs
__device__ __forceinline__ short f2bf(float f) {
    __bf16 h = (__bf16)f;
    return __builtin_bit_cast(short, h);
}

// raw barrier without the __syncthreads vmcnt(0) drain
__device__ __forceinline__ void raw_barrier() {
    asm volatile("s_barrier" ::: "memory");
}

// ---------------------------------------------------------------------------
// prep_w (verified) + fused dinv (blocks >= 112 do adj rowsums; disjoint data)
// ---------------------------------------------------------------------------
__global__ __launch_bounds__(256) void prep_w(
    const float* __restrict__ w1, const float* __restrict__ b1,
    const float* __restrict__ bn0_g, const float* __restrict__ bn0_b,
    const float* __restrict__ w2, const float* __restrict__ b2,
    const float* __restrict__ bn1_g, const float* __restrict__ bn1_b,
    const float* __restrict__ adj,
    short* __restrict__ w1t, short* __restrict__ w2t,
    float* __restrict__ b1f, float* __restrict__ b2f,
    float* __restrict__ dinv)
{
    if (blockIdx.x >= 112) {   // dinv part: one block per superpixel row
        __shared__ float red[256];
        const int n = blockIdx.x - 112;
        const int tt = threadIdx.x;
        float4 v = *(const float4*)&adj[(size_t)n * NSP + tt * 4];
        red[tt] = v.x + v.y + v.z + v.w;
        __syncthreads();
        for (int off = 128; off > 0; off >>= 1) {
            if (tt < off) red[tt] += red[tt + off];
            __syncthreads();
        }
        if (tt == 0) dinv[n] = rsqrtf(red[0] + 1.0f);
        return;
    }
    int t = blockIdx.x * 256 + threadIdx.x;
    if (t < 7 * 8 * 64 * 8) {
        int j = t & 7, lane = (t >> 3) & 63, nf = (t >> 9) & 7, ks = t >> 12;
        int ch = ks * 32 + (lane >> 4) * 8 + j;
        int d  = nf * 16 + (lane & 15);
        float v = (ch < 200) ? bn0_g[ch] * w1[ch * 128 + d] : 0.f;
        w1t[t] = f2bf(v);
    }
    if (t < 4 * 8 * 64 * 8) {
        int j = t & 7, lane = (t >> 3) & 63, nf = (t >> 9) & 7, ks = t >> 12;
        int k = ks * 32 + (lane >> 4) * 8 + j;
        int d = nf * 16 + (lane & 15);
        w2t[t] = f2bf(bn1_g[k] * w2[k * 128 + d]);
    }
    if (t < 128) {
        float s1 = b1[t], s2 = b2[t];
        for (int ch = 0; ch < 200; ++ch) s1 += bn0_b[ch] * w1[ch * 128 + t];
        for (int k = 0; k < 128; ++k)   s2 += bn1_b[k] * w2[k * 128 + t];
        b1f[t] = s1; b2f[t] = s2;
    }
}

// ---------------------------------------------------------------------------
// cnn_mfma (round-12 verified): 4 waves/block, xfT[d][pix] bf16
// ---------------------------------------------------------------------------
__global__ __launch_bounds__(256) void cnn_mfma(
    const float* __restrict__ x, const short* __restrict__ w1t,
    const float* __restrict__ b1f, const short* __restrict__ w2t,
    const float* __restrict__ b2f, short* __restrict__ xfT)
{
    __shared__ __align__(16) short a2[4][4][4][64][8];   // 64 KB
    const int t = threadIdx.x;
    const int w = t >> 6, l = t & 63;
    const int q = l >> 4, li = l & 15;
    const int pix0 = blockIdx.x * 256 + w * 64;

    f32x4 acc[4][8];
#pragma unroll
    for (int nf = 0; nf < 8; ++nf) {
        float bv = b1f[nf * 16 + li];
#pragma unroll
        for (int mf = 0; mf < 4; ++mf) acc[mf][nf] = (f32x4){bv, bv, bv, bv};
    }

    for (int ks = 0; ks < 7; ++ks) {
        bf16x8 a[4];
        if (ks < 6 || q == 0) {
            int k0 = ks * 32 + q * 8;
#pragma unroll
            for (int mf = 0; mf < 4; ++mf) {
                const float* sp = &x[(size_t)(pix0 + mf * 16 + li) * 200 + k0];
                float4 u = *(const float4*)sp;
                float4 v = *(const float4*)(sp + 4);
                a[mf][0] = f2bf(u.x); a[mf][1] = f2bf(u.y);
                a[mf][2] = f2bf(u.z); a[mf][3] = f2bf(u.w);
                a[mf][4] = f2bf(v.x); a[mf][5] = f2bf(v.y);
                a[mf][6] = f2bf(v.z); a[mf][7] = f2bf(v.w);
            }
        } else {
#pragma unroll
            for (int mf = 0; mf < 4; ++mf)
#pragma unroll
                for (int j = 0; j < 8; ++j) a[mf][j] = 0;
        }
#pragma unroll
        for (int nf = 0; nf < 8; ++nf) {
            bf16x8 b = *(const bf16x8*)&w1t[((ks * 8 + nf) * 64 + l) * 8];
#pragma unroll
            for (int mf = 0; mf < 4; ++mf)
                acc[mf][nf] = __builtin_amdgcn_mfma_f32_16x16x32_bf16(a[mf], b, acc[mf][nf], 0, 0, 0);
        }
    }

#pragma unroll
    for (int mf = 0; mf < 4; ++mf)
#pragma unroll
        for (int nf = 0; nf < 8; ++nf)
#pragma unroll
            for (int j = 0; j < 4; ++j) {
                float v = lrelu(acc[mf][nf][j]);
                int row = mf * 16 + q * 4 + j;
                int col = nf * 16 + li;
                int ks2 = col >> 5;
                int lane2 = (row & 15) + (((col & 31) >> 3) << 4);
                a2[w][ks2][mf][lane2][col & 7] = f2bf(v);
            }
    __syncthreads();

    f32x4 acc2[4][8];
#pragma unroll
    for (int nf = 0; nf < 8; ++nf) {
        float bv = b2f[nf * 16 + li];
#pragma unroll
        for (int mf = 0; mf < 4; ++mf) acc2[mf][nf] = (f32x4){bv, bv, bv, bv};
    }
#pragma unroll
    for (int ks = 0; ks < 4; ++ks) {
        bf16x8 a[4];
#pragma unroll
        for (int mf = 0; mf < 4; ++mf)
            a[mf] = *(const bf16x8*)&a2[w][ks][mf][l][0];
#pragma unroll
        for (int nf = 0; nf < 8; ++nf) {
            bf16x8 b = *(const bf16x8*)&w2t[((ks * 8 + nf) * 64 + l) * 8];
#pragma unroll
            for (int mf = 0; mf < 4; ++mf)
                acc2[mf][nf] = __builtin_amdgcn_mfma_f32_16x16x32_bf16(a[mf], b, acc2[mf][nf], 0, 0, 0);
        }
    }

#pragma unroll
    for (int mf = 0; mf < 4; ++mf)
#pragma unroll
        for (int nf = 0; nf < 8; ++nf) {
            bf16x4 p;
#pragma unroll
            for (int j = 0; j < 4; ++j) p[j] = f2bf(lrelu(acc2[mf][nf][j]));
            int d2 = nf * 16 + li;
            int pix = pix0 + mf * 16 + q * 4;
            *(bf16x4*)&xfT[(size_t)d2 * HWP + pix] = p;
        }
}

// ---------------------------------------------------------------------------
// pool_mfma (round-10/12 verified): LDS-staged + counted-vmcnt pipeline.
// grid (8 nblk, KC); block 256 = 4 waves. Q tile [64r][128n] fp32 = 32KB x2.
// ---------------------------------------------------------------------------
__device__ __forceinline__ void pool_loadB(bf16x8 (&dst)[4], const short* __restrict__ xfT,
                                           int dcol0, int rbase)
{
#pragma unroll
    for (int nf = 0; nf < 4; ++nf)
        dst[nf] = *(const bf16x8*)&xfT[(size_t)(dcol0 + nf * 16) * HWP + rbase];
}

__device__ __forceinline__ void pool_stage(const float* __restrict__ Q, float* dst,
                                           int r0t, int n0blk, int wid, int l)
{
#pragma unroll
    for (int i = 0; i < 8; ++i) {
        int o = (i * 4 + wid) * 1024 + l * 16;     // byte offset in 32KB tile
        int row = o >> 9;                          // 512B per row (128 fp32)
        int wrd = (o & 511) >> 2;                  // word-in-row 0..127
        const float* src = Q + (size_t)(r0t + row) * NSP + n0blk
                             + (wrd ^ (((row >> 3) & 3) << 4));
        __builtin_amdgcn_global_load_lds(
            (const __attribute__((address_space(1))) unsigned int*)src,
            (__attribute__((address_space(3))) unsigned int*)(dst + (o >> 2)),
            16, 0, 0);
    }
}

__global__ __launch_bounds__(256, 2) void pool_mfma(
    const float* __restrict__ Q, const short* __restrict__ xfT,
    float* __restrict__ P_part, float* __restrict__ qs_part)
{
    __shared__ __align__(16) float qtile[2][8192];   // 2 x 32KB
    const int t = threadIdx.x;
    const int wid = t >> 6, l = t & 63;
    const int q = l >> 4, li = l & 15;
    const int nw = (wid >> 1) * 64;
    const int d0 = (wid & 1) * 64;
    const int n0blk = blockIdx.x * 128;
    const int chunk = blockIdx.y;
    const int r0 = chunk * 1024;
    const int dcol0 = d0 + li;

    f32x4 acc[4][4];
    f32x4 accq[4];
#pragma unroll
    for (int mf = 0; mf < 4; ++mf) {
        accq[mf] = (f32x4){0.f, 0.f, 0.f, 0.f};
#pragma unroll
        for (int nf = 0; nf < 4; ++nf) acc[mf][nf] = (f32x4){0.f, 0.f, 0.f, 0.f};
    }
    bf16x8 bone;
    {
        short onev = (li == 0) ? (short)0x3F80 : (short)0;
#pragma unroll
        for (int j = 0; j < 8; ++j) bone[j] = onev;
    }

    // prologue: B(t0) + stage(t0)   [16 vmem ops in flight]
    bf16x8 bA[4], bB[4];
    pool_loadB(bA, xfT, dcol0, r0 + q * 8);
    pool_loadB(bB, xfT, dcol0, r0 + 32 + q * 8);
    pool_stage(Q, qtile[0], r0, n0blk, wid, l);

    for (int tile = 0; tile < 16; ++tile) {
        const int cur = tile & 1;
        raw_barrier();                               // prev compute's reads done
        bf16x8 nA[4], nB[4];
        if (tile < 15) {
            pool_loadB(nA, xfT, dcol0, r0 + (tile + 1) * 64 + q * 8);
            pool_loadB(nB, xfT, dcol0, r0 + (tile + 1) * 64 + 32 + q * 8);
            pool_stage(Q, qtile[cur ^ 1], r0 + (tile + 1) * 64, n0blk, wid, l);
            asm volatile("s_waitcnt vmcnt(16)" ::: "memory");   // tile-t ops done
        } else {
            asm volatile("s_waitcnt vmcnt(0)" ::: "memory");
        }
        raw_barrier();                               // stage(tile) visible
        __builtin_amdgcn_sched_barrier(0);
#pragma unroll
        for (int ks = 0; ks < 2; ++ks) {
            bf16x8 abf[4];
#pragma unroll
            for (int mf = 0; mf < 4; ++mf) {
#pragma unroll
                for (int j = 0; j < 8; ++j) {
                    int row = ks * 32 + q * 8 + j;           // (row>>3)&3 == q
                    int w2i = (nw + mf * 16 + li) ^ (q << 4);
                    abf[mf][j] = f2bf(qtile[cur][(row << 7) + w2i]);
                }
            }
#pragma unroll
            for (int mf = 0; mf < 4; ++mf) {
#pragma unroll
                for (int nf = 0; nf < 4; ++nf)
                    acc[mf][nf] = __builtin_amdgcn_mfma_f32_16x16x32_bf16(
                        abf[mf], (ks == 0) ? bA[nf] : bB[nf], acc[mf][nf], 0, 0, 0);
                if (d0 == 0)
                    accq[mf] = __builtin_amdgcn_mfma_f32_16x16x32_bf16(
                        abf[mf], bone, accq[mf], 0, 0, 0);
            }
        }
        if (tile < 15) {
#pragma unroll
            for (int nf = 0; nf < 4; ++nf) { bA[nf] = nA[nf]; bB[nf] = nB[nf]; }
        }
    }

#pragma unroll
    for (int mf = 0; mf < 4; ++mf)
#pragma unroll
        for (int nf = 0; nf < 4; ++nf)
#pragma unroll
            for (int j = 0; j < 4; ++j) {
                int n = n0blk + nw + mf * 16 + q * 4 + j;
                int d = d0 + nf * 16 + li;
                P_part[((size_t)chunk * NSP + n) * DCH + d] = acc[mf][nf][j];
            }
    if (d0 == 0 && li == 0)
#pragma unroll
        for (int mf = 0; mf < 4; ++mf)
#pragma unroll
            for (int j = 0; j < 4; ++j)
                qs_part[chunk * NSP + n0blk + nw + mf * 16 + q * 4 + j] = accq[mf][j];
}

// ---------------------------------------------------------------------------
__global__ __launch_bounds__(256) void reduce_h0(
    const float* __restrict__ P_part, const float* __restrict__ qs_part,
    float* __restrict__ h)
{
    const int i4 = blockIdx.x * 256 + threadIdx.x;
    const int n = i4 >> 5;
    f32x4 s = (f32x4){0.f, 0.f, 0.f, 0.f};
    const f32x4* P4 = (const f32x4*)P_part;
    for (int k = 0; k < KC; ++k) s += P4[(size_t)k * (NSP * DCH / 4) + i4];
    float qs = 0.f;
    for (int k = 0; k < KC; ++k) qs += qs_part[k * NSP + n];
    float inv = 1.f / qs;
    ((f32x4*)h)[i4] = s * inv;
}

// ---------------------------------------------------------------------------
// m1_k (verified): grid (64 r-tiles, 16 j-chunks of 64)
// ---------------------------------------------------------------------------
__global__ __launch_bounds__(256) void m1_k(
    const float* __restrict__ adj, const float* __restrict__ h,
    const float* __restrict__ dinv, const float* __restrict__ gg,
    const float* __restrict__ gb, float* __restrict__ m1p)
{
    __shared__ float adjL[16][64];
    __shared__ float hbL[64][128];
    const int r0 = blockIdx.x * 16;
    const int jc = blockIdx.y;
    const int j0 = jc * 64;
    const int t = threadIdx.x;
    const int d = t & 127, ph = t >> 7;

    for (int i = t; i < 16 * 64; i += 256) {
        int row = i >> 6, col = i & 63;
        adjL[row][col] = adj[(size_t)(r0 + row) * NSP + j0 + col];
    }
    for (int i = t; i < 64 * 128; i += 256) {
        int jr = i >> 7, dd = i & 127;
        int j = j0 + jr;
        hbL[jr][dd] = dinv[j] * (gg[dd] * h[(size_t)j * DCH + dd] + gb[dd]);
    }
    __syncthreads();

    float acc[8];
#pragma unroll
    for (int pp = 0; pp < 8; ++pp) acc[pp] = 0.f;
    for (int jj = 0; jj < 64; ++jj) {
        float hv = hbL[jj][d];
#pragma unroll
        for (int pp = 0; pp < 8; ++pp)
            acc[pp] += adjL[ph * 8 + pp][jj] * hv;
    }
#pragma unroll
    for (int pp = 0; pp < 8; ++pp)
        m1p[(size_t)jc * (NSP * DCH) + (size_t)(r0 + ph * 8 + pp) * DCH + d] = acc[pp];
}

// ---------------------------------------------------------------------------
// gcnw_k (verified) + fused htb write
// ---------------------------------------------------------------------------
__global__ __launch_bounds__(256) void gcnw_k(
    const float* __restrict__ m1p, const float* __restrict__ h,
    const float* __restrict__ dinv, const float* __restrict__ gg,
    const float* __restrict__ gb, const float* __restrict__ W,
    const float* __restrict__ bias, float* __restrict__ hout,
    short* __restrict__ htb)
{
    __shared__ float ms[16 * 128];
    __shared__ float WL[64 * 128];
    const int r0 = blockIdx.x * 16;
    const int t = threadIdx.x;
    for (int i = t; i < 2048; i += 256) {
        int r = r0 + (i >> 7), dd = i & 127;
        float hbr = dinv[r] * (gg[dd] * h[(size_t)r * DCH + dd] + gb[dd]);
        float s = hbr;
#pragma unroll
        for (int kc = 0; kc < JC; ++kc)
            s += m1p[(size_t)kc * (NSP * DCH) + (size_t)r0 * DCH + i];
        ms[i] = dinv[r] * s;
    }
    const int e = t & 127, ph = t >> 7;
    float acc[8];
#pragma unroll
    for (int pp = 0; pp < 8; ++pp) acc[pp] = bias[e];
    for (int sub = 0; sub < 2; ++sub) {
        __syncthreads();
        for (int i = t; i < 64 * 128; i += 256)
            WL[i] = W[(size_t)sub * 64 * 128 + i];
        __syncthreads();
        for (int dd = 0; dd < 64; ++dd) {
            float wv = WL[dd * 128 + e];
#pragma unroll
            for (int pp = 0; pp < 8; ++pp)
                acc[pp] += ms[(ph * 8 + pp) * 128 + sub * 64 + dd] * wv;
        }
    }
#pragma unroll
    for (int pp = 0; pp < 8; ++pp) {
        int r = r0 + ph * 8 + pp;
        float v = lrelu(acc[pp]);
        hout[(size_t)r * DCH + e] = v;
        int lane = (((r >> 3) & 3) << 4) + (e & 15);
        htb[(((r >> 5) * 8 + (e >> 4)) * 64 + lane) * 8 + (r & 7)] = f2bf(v);
    }
}

// ---------------------------------------------------------------------------
// out_mfma (round-10/12 verified): LDS-staged + counted-vmcnt pipeline.
// ---------------------------------------------------------------------------
__device__ __forceinline__ void out_loadB(bf16x8 (&dst)[4], const short* __restrict__ htb,
                                          int ks, int nfbase, int l)
{
#pragma unroll
    for (int nf = 0; nf < 4; ++nf)
        dst[nf] = *(const bf16x8*)&htb[((ks * 8 + nfbase + nf) * 64 + l) * 8];
}

__device__ __forceinline__ void stage_q(const float* __restrict__ Q, float* dst,
                                        int r0, int kbase, int wid, int l)
{
#pragma unroll
    for (int i = 0; i < 8; ++i) {
        int o = (i * 4 + wid) * 1024 + l * 16;      // byte offset in 32KB tile
        int row = o >> 8;                           // 256B per row (64 fp32)
        int bin = o & 255;                          // 16B-aligned
        const float* src = Q + (size_t)(r0 + row) * NSP + kbase
                             + ((bin ^ ((row & 7) << 5)) >> 2);
        __builtin_amdgcn_global_load_lds(
            (const __attribute__((address_space(1))) unsigned int*)src,
            (__attribute__((address_space(3))) unsigned int*)(dst + (o >> 2)),
            16, 0, 0);
    }
}

__global__ __launch_bounds__(256, 2) void out_mfma(
    const float* __restrict__ Q, const short* __restrict__ htb,
    float* __restrict__ out)
{
    __shared__ __align__(16) float qs[2][8192];     // 2 x 32KB
    const int t = threadIdx.x;
    const int wid = t >> 6, l = t & 63;
    const int q = l >> 4, li = l & 15;
    const int r0 = blockIdx.x * 128;
    const int rw = (wid >> 1) * 64;
    const int d0 = (wid & 1) * 64;
    const int nfb = d0 >> 4;

    f32x4 acc[4][4];
#pragma unroll
    for (int mf = 0; mf < 4; ++mf)
#pragma unroll
        for (int nf = 0; nf < 4; ++nf) acc[mf][nf] = (f32x4){0.f, 0.f, 0.f, 0.f};

    bf16x8 bA[4], bB[4];
    out_loadB(bA, htb, 0, nfb, l);
    out_loadB(bB, htb, 1, nfb, l);
    stage_q(Q, qs[0], r0, 0, wid, l);

    for (int tile = 0; tile < 16; ++tile) {
        const int cur = tile & 1;
        raw_barrier();                               // prev compute's reads done
        bf16x8 nA[4], nB[4];
        if (tile < 15) {
            out_loadB(nA, htb, (tile + 1) * 2,     nfb, l);
            out_loadB(nB, htb, (tile + 1) * 2 + 1, nfb, l);
            stage_q(Q, qs[cur ^ 1], r0, (tile + 1) * 64, wid, l);
            asm volatile("s_waitcnt vmcnt(16)" ::: "memory");
        } else {
            asm volatile("s_waitcnt vmcnt(0)" ::: "memory");
        }
        raw_barrier();                               // stage(tile) visible
        __builtin_amdgcn_sched_barrier(0);
#pragma unroll
        for (int ks = 0; ks < 2; ++ks) {
            bf16x8 abf[4];
#pragma unroll
            for (int mf = 0; mf < 4; ++mf) {
                int rl = rw + mf * 16 + li;
                int koff = (ks * 32 + q * 8) << 2;
                const float* p = &qs[cur][(rl << 6) + ((koff ^ ((rl & 7) << 5)) >> 2)];
                float4 u = *(const float4*)p;
                float4 v = *(const float4*)(p + 4);
                abf[mf][0] = f2bf(u.x); abf[mf][1] = f2bf(u.y);
                abf[mf][2] = f2bf(u.z); abf[mf][3] = f2bf(u.w);
                abf[mf][4] = f2bf(v.x); abf[mf][5] = f2bf(v.y);
                abf[mf][6] = f2bf(v.z); abf[mf][7] = f2bf(v.w);
            }
            if (ks == 0) {
#pragma unroll
                for (int mf = 0; mf < 4; ++mf)
#pragma unroll
                    for (int nf = 0; nf < 4; ++nf)
                        acc[mf][nf] = __builtin_amdgcn_mfma_f32_16x16x32_bf16(abf[mf], bA[nf], acc[mf][nf], 0, 0, 0);
            } else {
#pragma unroll
                for (int mf = 0; mf < 4; ++mf)
#pragma unroll
                    for (int nf = 0; nf < 4; ++nf)
                        acc[mf][nf] = __builtin_amdgcn_mfma_f32_16x16x32_bf16(abf[mf], bB[nf], acc[mf][nf], 0, 0, 0);
            }
        }
        if (tile < 15) {
#pragma unroll
            for (int nf = 0; nf < 4; ++nf) { bA[nf] = nA[nf]; bB[nf] = nB[nf]; }
        }
    }

#pragma unroll
    for (int mf = 0; mf < 4; ++mf)
#pragma unroll
        for (int nf = 0; nf < 4; ++nf)
#pragma unroll
            for (int j = 0; j < 4; ++j)
                out[(size_t)(r0 + rw + mf * 16 + q * 4 + j) * DCH + d0 + nf * 16 + li] = acc[mf][nf][j];
}

// ---------------------------------------------------------------------------
extern "C" void kernel_launch(void* const* d_in, const int* in_sizes, int n_in,
                              void* d_out, int out_size, void* d_ws, size_t ws_size,
                              hipStream_t stream)
{
    const float* x      = (const float*)d_in[0];
    const float* Q      = (const float*)d_in[1];
    const float* adj    = (const float*)d_in[2];
    const float* bn0_g  = (const float*)d_in[3];
    const float* bn0_b  = (const float*)d_in[4];
    const float* w1     = (const float*)d_in[5];
    const float* b1     = (const float*)d_in[6];
    const float* bn1_g  = (const float*)d_in[7];
    const float* bn1_b  = (const float*)d_in[8];
    const float* w2     = (const float*)d_in[9];
    const float* b2     = (const float*)d_in[10];
    const float* gbn_g  = (const float*)d_in[11];
    const float* gbn_b  = (const float*)d_in[12];
    const float* gcn_w  = (const float*)d_in[13];
    const float* gcn_b  = (const float*)d_in[14];

    float* out = (float*)d_out;
    float* ws  = (float*)d_ws;

    // workspace layout (float units)
    float* P_part  = ws;                                   // 8,388,608
    float* qs_part = P_part + (size_t)KC * NSP * DCH;      // 65,536
    float* hA      = qs_part + (size_t)KC * NSP;           // 131,072
    float* hB      = hA + NSP * DCH;                       // 131,072
    float* dinvb   = hB + NSP * DCH;                       // 1,024
    short* htb     = (short*)(dinvb + NSP);                // 131,072 bf16
    short* w1t     = (short*)((float*)htb + 65536);        // 28,672 bf16
    short* w2t     = (short*)((float*)w1t + 14336);        // 16,384 bf16
    float* b1f     = (float*)w2t + 8192;                   // 128
    float* b2f     = b1f + 128;                            // 128
    // GCN partials overlay P_part (dead after reduce_h0)
    float* m1p     = P_part;
    // xfT lives in the (currently dead) d_out buffer
    short* xfT     = (short*)d_out;

    prep_w<<<112 + NSP, 256, 0, stream>>>(w1, b1, bn0_g, bn0_b, w2, b2,
                                          bn1_g, bn1_b, adj,
                                          w1t, w2t, b1f, b2f, dinvb);
    cnn_mfma<<<HWP / 256, 256, 0, stream>>>(x, w1t, b1f, w2t, b2f, xfT);
    pool_mfma<<<dim3(NSP / 128, KC), 256, 0, stream>>>(Q, xfT, P_part, qs_part);
    reduce_h0<<<(NSP * DCH / 4) / 256, 256, 0, stream>>>(P_part, qs_part, hA);

    const float* hcur = hA;
    float* hnext = hB;
    for (int i = 0; i < 3; ++i) {
        m1_k<<<dim3(NSP / 16, JC), 256, 0, stream>>>(adj, hcur, dinvb,
                                                     gbn_g + i * DCH, gbn_b + i * DCH, m1p);
        gcnw_k<<<NSP / 16, 256, 0, stream>>>(m1p, hcur, dinvb,
                                             gbn_g + i * DCH, gbn_b + i * DCH,
                                             gcn_w + (size_t)i * DCH * DCH,
                                             gcn_b + i * DCH, hnext, htb);
        const float* tmp = hcur;
        hcur = hnext;
        hnext = (float*)tmp;
    }

    out_mfma<<<HWP / 128, 256, 0, stream>>>(Q, htb, out);
}

// Round 15
// 261.559 us; speedup vs baseline: 1.2327x; 1.0352x over previous
//
#include <hip/hip_runtime.h>

#define HWP 65536
#define NSP 1024
#define DCH 128
#define KC  64          // pooling k-chunks (rows per chunk = 1024)
#define JC  16          // m1 j-chunks (64 j's per chunk)

typedef float f32x4 __attribute__((ext_vector_type(4)));
typedef short bf16x8 __attribute__((ext_vector_type(8)));
typedef short bf16x4 __attribute__((ext_vector_type(4)));

__device__ __forceinline__ float lrelu(float v) { return v > 0.f ? v : 0.01f * v; }

// native conversion -> compiler emits v_cvt_pk_bf16_f32 pairs
__device__ __forceinline__ short f2bf(float f) {
    __bf16 h = (__bf16)f;
    return __builtin_bit_cast(short, h);
}

// raw barrier without the __syncthreads vmcnt(0) drain
__device__ __forceinline__ void raw_barrier() {
    asm volatile("s_barrier" ::: "memory");
}

// ---------------------------------------------------------------------------
// prep_w (verified) + fused dinv (blocks >= 112 do adj rowsums; disjoint data)
// ---------------------------------------------------------------------------
__global__ __launch_bounds__(256) void prep_w(
    const float* __restrict__ w1, const float* __restrict__ b1,
    const float* __restrict__ bn0_g, const float* __restrict__ bn0_b,
    const float* __restrict__ w2, const float* __restrict__ b2,
    const float* __restrict__ bn1_g, const float* __restrict__ bn1_b,
    const float* __restrict__ adj,
    short* __restrict__ w1t, short* __restrict__ w2t,
    float* __restrict__ b1f, float* __restrict__ b2f,
    float* __restrict__ dinv)
{
    if (blockIdx.x >= 112) {   // dinv part: one block per superpixel row
        __shared__ float red[256];
        const int n = blockIdx.x - 112;
        const int tt = threadIdx.x;
        float4 v = *(const float4*)&adj[(size_t)n * NSP + tt * 4];
        red[tt] = v.x + v.y + v.z + v.w;
        __syncthreads();
        for (int off = 128; off > 0; off >>= 1) {
            if (tt < off) red[tt] += red[tt + off];
            __syncthreads();
        }
        if (tt == 0) dinv[n] = rsqrtf(red[0] + 1.0f);
        return;
    }
    int t = blockIdx.x * 256 + threadIdx.x;
    if (t < 7 * 8 * 64 * 8) {
        int j = t & 7, lane = (t >> 3) & 63, nf = (t >> 9) & 7, ks = t >> 12;
        int ch = ks * 32 + (lane >> 4) * 8 + j;
        int d  = nf * 16 + (lane & 15);
        float v = (ch < 200) ? bn0_g[ch] * w1[ch * 128 + d] : 0.f;
        w1t[t] = f2bf(v);
    }
    if (t < 4 * 8 * 64 * 8) {
        int j = t & 7, lane = (t >> 3) & 63, nf = (t >> 9) & 7, ks = t >> 12;
        int k = ks * 32 + (lane >> 4) * 8 + j;
        int d = nf * 16 + (lane & 15);
        w2t[t] = f2bf(bn1_g[k] * w2[k * 128 + d]);
    }
    if (t < 128) {
        float s1 = b1[t], s2 = b2[t];
        for (int ch = 0; ch < 200; ++ch) s1 += bn0_b[ch] * w1[ch * 128 + t];
        for (int k = 0; k < 128; ++k)   s2 += bn1_b[k] * w2[k * 128 + t];
        b1f[t] = s1; b2f[t] = s2;
    }
}

// ---------------------------------------------------------------------------
// cnn_mfma (round-12 verified): 4 waves/block, xfT[d][pix] bf16
// ---------------------------------------------------------------------------
__global__ __launch_bounds__(256) void cnn_mfma(
    const float* __restrict__ x, const short* __restrict__ w1t,
    const float* __restrict__ b1f, const short* __restrict__ w2t,
    const float* __restrict__ b2f, short* __restrict__ xfT)
{
    __shared__ __align__(16) short a2[4][4][4][64][8];   // 64 KB
    const int t = threadIdx.x;
    const int w = t >> 6, l = t & 63;
    const int q = l >> 4, li = l & 15;
    const int pix0 = blockIdx.x * 256 + w * 64;

    f32x4 acc[4][8];
#pragma unroll
    for (int nf = 0; nf < 8; ++nf) {
        float bv = b1f[nf * 16 + li];
#pragma unroll
        for (int mf = 0; mf < 4; ++mf) acc[mf][nf] = (f32x4){bv, bv, bv, bv};
    }

    for (int ks = 0; ks < 7; ++ks) {
        bf16x8 a[4];
        if (ks < 6 || q == 0) {
            int k0 = ks * 32 + q * 8;
#pragma unroll
            for (int mf = 0; mf < 4; ++mf) {
                const float* sp = &x[(size_t)(pix0 + mf * 16 + li) * 200 + k0];
                float4 u = *(const float4*)sp;
                float4 v = *(const float4*)(sp + 4);
                a[mf][0] = f2bf(u.x); a[mf][1] = f2bf(u.y);
                a[mf][2] = f2bf(u.z); a[mf][3] = f2bf(u.w);
                a[mf][4] = f2bf(v.x); a[mf][5] = f2bf(v.y);
                a[mf][6] = f2bf(v.z); a[mf][7] = f2bf(v.w);
            }
        } else {
#pragma unroll
            for (int mf = 0; mf < 4; ++mf)
#pragma unroll
                for (int j = 0; j < 8; ++j) a[mf][j] = 0;
        }
#pragma unroll
        for (int nf = 0; nf < 8; ++nf) {
            bf16x8 b = *(const bf16x8*)&w1t[((ks * 8 + nf) * 64 + l) * 8];
#pragma unroll
            for (int mf = 0; mf < 4; ++mf)
                acc[mf][nf] = __builtin_amdgcn_mfma_f32_16x16x32_bf16(a[mf], b, acc[mf][nf], 0, 0, 0);
        }
    }

#pragma unroll
    for (int mf = 0; mf < 4; ++mf)
#pragma unroll
        for (int nf = 0; nf < 8; ++nf)
#pragma unroll
            for (int j = 0; j < 4; ++j) {
                float v = lrelu(acc[mf][nf][j]);
                int row = mf * 16 + q * 4 + j;
                int col = nf * 16 + li;
                int ks2 = col >> 5;
                int lane2 = (row & 15) + (((col & 31) >> 3) << 4);
                a2[w][ks2][mf][lane2][col & 7] = f2bf(v);
            }
    __syncthreads();

    f32x4 acc2[4][8];
#pragma unroll
    for (int nf = 0; nf < 8; ++nf) {
        float bv = b2f[nf * 16 + li];
#pragma unroll
        for (int mf = 0; mf < 4; ++mf) acc2[mf][nf] = (f32x4){bv, bv, bv, bv};
    }
#pragma unroll
    for (int ks = 0; ks < 4; ++ks) {
        bf16x8 a[4];
#pragma unroll
        for (int mf = 0; mf < 4; ++mf)
            a[mf] = *(const bf16x8*)&a2[w][ks][mf][l][0];
#pragma unroll
        for (int nf = 0; nf < 8; ++nf) {
            bf16x8 b = *(const bf16x8*)&w2t[((ks * 8 + nf) * 64 + l) * 8];
#pragma unroll
            for (int mf = 0; mf < 4; ++mf)
                acc2[mf][nf] = __builtin_amdgcn_mfma_f32_16x16x32_bf16(a[mf], b, acc2[mf][nf], 0, 0, 0);
        }
    }

#pragma unroll
    for (int mf = 0; mf < 4; ++mf)
#pragma unroll
        for (int nf = 0; nf < 8; ++nf) {
            bf16x4 p;
#pragma unroll
            for (int j = 0; j < 4; ++j) p[j] = f2bf(lrelu(acc2[mf][nf][j]));
            int d2 = nf * 16 + li;
            int pix = pix0 + mf * 16 + q * 4;
            *(bf16x4*)&xfT[(size_t)d2 * HWP + pix] = p;
        }
}

// ---------------------------------------------------------------------------
// pool_mfma (round-10/12 verified) + XCD-aware block swizzle:
// 1D grid 512; decode so each XCD owns 8 complete chunks -> the 8 n-blocks
// sharing a Q-chunk/xfT-slice land on ONE XCD's L2 (kills 8x L3 duplication).
// ---------------------------------------------------------------------------
__device__ __forceinline__ void pool_loadB(bf16x8 (&dst)[4], const short* __restrict__ xfT,
                                           int dcol0, int rbase)
{
#pragma unroll
    for (int nf = 0; nf < 4; ++nf)
        dst[nf] = *(const bf16x8*)&xfT[(size_t)(dcol0 + nf * 16) * HWP + rbase];
}

__device__ __forceinline__ void pool_stage(const float* __restrict__ Q, float* dst,
                                           int r0t, int n0blk, int wid, int l)
{
#pragma unroll
    for (int i = 0; i < 8; ++i) {
        int o = (i * 4 + wid) * 1024 + l * 16;     // byte offset in 32KB tile
        int row = o >> 9;                          // 512B per row (128 fp32)
        int wrd = (o & 511) >> 2;                  // word-in-row 0..127
        const float* src = Q + (size_t)(r0t + row) * NSP + n0blk
                             + (wrd ^ (((row >> 3) & 3) << 4));
        __builtin_amdgcn_global_load_lds(
            (const __attribute__((address_space(1))) unsigned int*)src,
            (__attribute__((address_space(3))) unsigned int*)(dst + (o >> 2)),
            16, 0, 0);
    }
}

__global__ __launch_bounds__(256, 2) void pool_mfma(
    const float* __restrict__ Q, const short* __restrict__ xfT,
    float* __restrict__ P_part, float* __restrict__ qs_part)
{
    __shared__ __align__(16) float qtile[2][8192];   // 2 x 32KB
    const int t = threadIdx.x;
    const int wid = t >> 6, l = t & 63;
    const int q = l >> 4, li = l & 15;
    const int nw = (wid >> 1) * 64;
    const int d0 = (wid & 1) * 64;
    // XCD swizzle: bid%8 = XCD (observed round-robin); give XCD k chunks 8k..8k+7
    const int bid   = blockIdx.x;          // 0..511
    const int xcd   = bid & 7;
    const int local = bid >> 3;            // 0..63
    const int n0blk = (local & 7) * 128;
    const int chunk = (local >> 3) | (xcd << 3);
    const int r0 = chunk * 1024;
    const int dcol0 = d0 + li;

    f32x4 acc[4][4];
    f32x4 accq[4];
#pragma unroll
    for (int mf = 0; mf < 4; ++mf) {
        accq[mf] = (f32x4){0.f, 0.f, 0.f, 0.f};
#pragma unroll
        for (int nf = 0; nf < 4; ++nf) acc[mf][nf] = (f32x4){0.f, 0.f, 0.f, 0.f};
    }
    bf16x8 bone;
    {
        short onev = (li == 0) ? (short)0x3F80 : (short)0;
#pragma unroll
        for (int j = 0; j < 8; ++j) bone[j] = onev;
    }

    // prologue: B(t0) + stage(t0)   [16 vmem ops in flight]
    bf16x8 bA[4], bB[4];
    pool_loadB(bA, xfT, dcol0, r0 + q * 8);
    pool_loadB(bB, xfT, dcol0, r0 + 32 + q * 8);
    pool_stage(Q, qtile[0], r0, n0blk, wid, l);

    for (int tile = 0; tile < 16; ++tile) {
        const int cur = tile & 1;
        raw_barrier();                               // prev compute's reads done
        bf16x8 nA[4], nB[4];
        if (tile < 15) {
            pool_loadB(nA, xfT, dcol0, r0 + (tile + 1) * 64 + q * 8);
            pool_loadB(nB, xfT, dcol0, r0 + (tile + 1) * 64 + 32 + q * 8);
            pool_stage(Q, qtile[cur ^ 1], r0 + (tile + 1) * 64, n0blk, wid, l);
            asm volatile("s_waitcnt vmcnt(16)" ::: "memory");   // tile-t ops done
        } else {
            asm volatile("s_waitcnt vmcnt(0)" ::: "memory");
        }
        raw_barrier();                               // stage(tile) visible
        __builtin_amdgcn_sched_barrier(0);
#pragma unroll
        for (int ks = 0; ks < 2; ++ks) {
            bf16x8 abf[4];
#pragma unroll
            for (int mf = 0; mf < 4; ++mf) {
#pragma unroll
                for (int j = 0; j < 8; ++j) {
                    int row = ks * 32 + q * 8 + j;           // (row>>3)&3 == q
                    int w2i = (nw + mf * 16 + li) ^ (q << 4);
                    abf[mf][j] = f2bf(qtile[cur][(row << 7) + w2i]);
                }
            }
#pragma unroll
            for (int mf = 0; mf < 4; ++mf) {
#pragma unroll
                for (int nf = 0; nf < 4; ++nf)
                    acc[mf][nf] = __builtin_amdgcn_mfma_f32_16x16x32_bf16(
                        abf[mf], (ks == 0) ? bA[nf] : bB[nf], acc[mf][nf], 0, 0, 0);
                if (d0 == 0)
                    accq[mf] = __builtin_amdgcn_mfma_f32_16x16x32_bf16(
                        abf[mf], bone, accq[mf], 0, 0, 0);
            }
        }
        if (tile < 15) {
#pragma unroll
            for (int nf = 0; nf < 4; ++nf) { bA[nf] = nA[nf]; bB[nf] = nB[nf]; }
        }
    }

#pragma unroll
    for (int mf = 0; mf < 4; ++mf)
#pragma unroll
        for (int nf = 0; nf < 4; ++nf)
#pragma unroll
            for (int j = 0; j < 4; ++j) {
                int n = n0blk + nw + mf * 16 + q * 4 + j;
                int d = d0 + nf * 16 + li;
                P_part[((size_t)chunk * NSP + n) * DCH + d] = acc[mf][nf][j];
            }
    if (d0 == 0 && li == 0)
#pragma unroll
        for (int mf = 0; mf < 4; ++mf)
#pragma unroll
            for (int j = 0; j < 4; ++j)
                qs_part[chunk * NSP + n0blk + nw + mf * 16 + q * 4 + j] = accq[mf][j];
}

// ---------------------------------------------------------------------------
__global__ __launch_bounds__(256) void reduce_h0(
    const float* __restrict__ P_part, const float* __restrict__ qs_part,
    float* __restrict__ h)
{
    const int i4 = blockIdx.x * 256 + threadIdx.x;
    const int n = i4 >> 5;
    f32x4 s = (f32x4){0.f, 0.f, 0.f, 0.f};
    const f32x4* P4 = (const f32x4*)P_part;
    for (int k = 0; k < KC; ++k) s += P4[(size_t)k * (NSP * DCH / 4) + i4];
    float qs = 0.f;
    for (int k = 0; k < KC; ++k) qs += qs_part[k * NSP + n];
    float inv = 1.f / qs;
    ((f32x4*)h)[i4] = s * inv;
}

// ---------------------------------------------------------------------------
// m1_k (verified): grid (64 r-tiles, 16 j-chunks of 64)
// ---------------------------------------------------------------------------
__global__ __launch_bounds__(256) void m1_k(
    const float* __restrict__ adj, const float* __restrict__ h,
    const float* __restrict__ dinv, const float* __restrict__ gg,
    const float* __restrict__ gb, float* __restrict__ m1p)
{
    __shared__ float adjL[16][64];
    __shared__ float hbL[64][128];
    const int r0 = blockIdx.x * 16;
    const int jc = blockIdx.y;
    const int j0 = jc * 64;
    const int t = threadIdx.x;
    const int d = t & 127, ph = t >> 7;

    for (int i = t; i < 16 * 64; i += 256) {
        int row = i >> 6, col = i & 63;
        adjL[row][col] = adj[(size_t)(r0 + row) * NSP + j0 + col];
    }
    for (int i = t; i < 64 * 128; i += 256) {
        int jr = i >> 7, dd = i & 127;
        int j = j0 + jr;
        hbL[jr][dd] = dinv[j] * (gg[dd] * h[(size_t)j * DCH + dd] + gb[dd]);
    }
    __syncthreads();

    float acc[8];
#pragma unroll
    for (int pp = 0; pp < 8; ++pp) acc[pp] = 0.f;
    for (int jj = 0; jj < 64; ++jj) {
        float hv = hbL[jj][d];
#pragma unroll
        for (int pp = 0; pp < 8; ++pp)
            acc[pp] += adjL[ph * 8 + pp][jj] * hv;
    }
#pragma unroll
    for (int pp = 0; pp < 8; ++pp)
        m1p[(size_t)jc * (NSP * DCH) + (size_t)(r0 + ph * 8 + pp) * DCH + d] = acc[pp];
}

// ---------------------------------------------------------------------------
// gcnw_k (verified) + fused htb write
// ---------------------------------------------------------------------------
__global__ __launch_bounds__(256) void gcnw_k(
    const float* __restrict__ m1p, const float* __restrict__ h,
    const float* __restrict__ dinv, const float* __restrict__ gg,
    const float* __restrict__ gb, const float* __restrict__ W,
    const float* __restrict__ bias, float* __restrict__ hout,
    short* __restrict__ htb)
{
    __shared__ float ms[16 * 128];
    __shared__ float WL[64 * 128];
    const int r0 = blockIdx.x * 16;
    const int t = threadIdx.x;
    for (int i = t; i < 2048; i += 256) {
        int r = r0 + (i >> 7), dd = i & 127;
        float hbr = dinv[r] * (gg[dd] * h[(size_t)r * DCH + dd] + gb[dd]);
        float s = hbr;
#pragma unroll
        for (int kc = 0; kc < JC; ++kc)
            s += m1p[(size_t)kc * (NSP * DCH) + (size_t)r0 * DCH + i];
        ms[i] = dinv[r] * s;
    }
    const int e = t & 127, ph = t >> 7;
    float acc[8];
#pragma unroll
    for (int pp = 0; pp < 8; ++pp) acc[pp] = bias[e];
    for (int sub = 0; sub < 2; ++sub) {
        __syncthreads();
        for (int i = t; i < 64 * 128; i += 256)
            WL[i] = W[(size_t)sub * 64 * 128 + i];
        __syncthreads();
        for (int dd = 0; dd < 64; ++dd) {
            float wv = WL[dd * 128 + e];
#pragma unroll
            for (int pp = 0; pp < 8; ++pp)
                acc[pp] += ms[(ph * 8 + pp) * 128 + sub * 64 + dd] * wv;
        }
    }
#pragma unroll
    for (int pp = 0; pp < 8; ++pp) {
        int r = r0 + ph * 8 + pp;
        float v = lrelu(acc[pp]);
        hout[(size_t)r * DCH + e] = v;
        int lane = (((r >> 3) & 3) << 4) + (e & 15);
        htb[(((r >> 5) * 8 + (e >> 4)) * 64 + lane) * 8 + (r & 7)] = f2bf(v);
    }
}

// ---------------------------------------------------------------------------
// out_mfma (round-10/12 verified): LDS-staged + counted-vmcnt pipeline.
// ---------------------------------------------------------------------------
__device__ __forceinline__ void out_loadB(bf16x8 (&dst)[4], const short* __restrict__ htb,
                                          int ks, int nfbase, int l)
{
#pragma unroll
    for (int nf = 0; nf < 4; ++nf)
        dst[nf] = *(const bf16x8*)&htb[((ks * 8 + nfbase + nf) * 64 + l) * 8];
}

__device__ __forceinline__ void stage_q(const float* __restrict__ Q, float* dst,
                                        int r0, int kbase, int wid, int l)
{
#pragma unroll
    for (int i = 0; i < 8; ++i) {
        int o = (i * 4 + wid) * 1024 + l * 16;      // byte offset in 32KB tile
        int row = o >> 8;                           // 256B per row (64 fp32)
        int bin = o & 255;                          // 16B-aligned
        const float* src = Q + (size_t)(r0 + row) * NSP + kbase
                             + ((bin ^ ((row & 7) << 5)) >> 2);
        __builtin_amdgcn_global_load_lds(
            (const __attribute__((address_space(1))) unsigned int*)src,
            (__attribute__((address_space(3))) unsigned int*)(dst + (o >> 2)),
            16, 0, 0);
    }
}

__global__ __launch_bounds__(256, 2) void out_mfma(
    const float* __restrict__ Q, const short* __restrict__ htb,
    float* __restrict__ out)
{
    __shared__ __align__(16) float qs[2][8192];     // 2 x 32KB
    const int t = threadIdx.x;
    const int wid = t >> 6, l = t & 63;
    const int q = l >> 4, li = l & 15;
    const int r0 = blockIdx.x * 128;
    const int rw = (wid >> 1) * 64;
    const int d0 = (wid & 1) * 64;
    const int nfb = d0 >> 4;

    f32x4 acc[4][4];
#pragma unroll
    for (int mf = 0; mf < 4; ++mf)
#pragma unroll
        for (int nf = 0; nf < 4; ++nf) acc[mf][nf] = (f32x4){0.f, 0.f, 0.f, 0.f};

    bf16x8 bA[4], bB[4];
    out_loadB(bA, htb, 0, nfb, l);
    out_loadB(bB, htb, 1, nfb, l);
    stage_q(Q, qs[0], r0, 0, wid, l);

    for (int tile = 0; tile < 16; ++tile) {
        const int cur = tile & 1;
        raw_barrier();                               // prev compute's reads done
        bf16x8 nA[4], nB[4];
        if (tile < 15) {
            out_loadB(nA, htb, (tile + 1) * 2,     nfb, l);
            out_loadB(nB, htb, (tile + 1) * 2 + 1, nfb, l);
            stage_q(Q, qs[cur ^ 1], r0, (tile + 1) * 64, wid, l);
            asm volatile("s_waitcnt vmcnt(16)" ::: "memory");
        } else {
            asm volatile("s_waitcnt vmcnt(0)" ::: "memory");
        }
        raw_barrier();                               // stage(tile) visible
        __builtin_amdgcn_sched_barrier(0);
#pragma unroll
        for (int ks = 0; ks < 2; ++ks) {
            bf16x8 abf[4];
#pragma unroll
            for (int mf = 0; mf < 4; ++mf) {
                int rl = rw + mf * 16 + li;
                int koff = (ks * 32 + q * 8) << 2;
                const float* p = &qs[cur][(rl << 6) + ((koff ^ ((rl & 7) << 5)) >> 2)];
                float4 u = *(const float4*)p;
                float4 v = *(const float4*)(p + 4);
                abf[mf][0] = f2bf(u.x); abf[mf][1] = f2bf(u.y);
                abf[mf][2] = f2bf(u.z); abf[mf][3] = f2bf(u.w);
                abf[mf][4] = f2bf(v.x); abf[mf][5] = f2bf(v.y);
                abf[mf][6] = f2bf(v.z); abf[mf][7] = f2bf(v.w);
            }
            if (ks == 0) {
#pragma unroll
                for (int mf = 0; mf < 4; ++mf)
#pragma unroll
                    for (int nf = 0; nf < 4; ++nf)
                        acc[mf][nf] = __builtin_amdgcn_mfma_f32_16x16x32_bf16(abf[mf], bA[nf], acc[mf][nf], 0, 0, 0);
            } else {
#pragma unroll
                for (int mf = 0; mf < 4; ++mf)
#pragma unroll
                    for (int nf = 0; nf < 4; ++nf)
                        acc[mf][nf] = __builtin_amdgcn_mfma_f32_16x16x32_bf16(abf[mf], bB[nf], acc[mf][nf], 0, 0, 0);
            }
        }
        if (tile < 15) {
#pragma unroll
            for (int nf = 0; nf < 4; ++nf) { bA[nf] = nA[nf]; bB[nf] = nB[nf]; }
        }
    }

#pragma unroll
    for (int mf = 0; mf < 4; ++mf)
#pragma unroll
        for (int nf = 0; nf < 4; ++nf)
#pragma unroll
            for (int j = 0; j < 4; ++j)
                out[(size_t)(r0 + rw + mf * 16 + q * 4 + j) * DCH + d0 + nf * 16 + li] = acc[mf][nf][j];
}

// ---------------------------------------------------------------------------
extern "C" void kernel_launch(void* const* d_in, const int* in_sizes, int n_in,
                              void* d_out, int out_size, void* d_ws, size_t ws_size,
                              hipStream_t stream)
{
    const float* x      = (const float*)d_in[0];
    const float* Q      = (const float*)d_in[1];
    const float* adj    = (const float*)d_in[2];
    const float* bn0_g  = (const float*)d_in[3];
    const float* bn0_b  = (const float*)d_in[4];
    const float* w1     = (const float*)d_in[5];
    const float* b1     = (const float*)d_in[6];
    const float* bn1_g  = (const float*)d_in[7];
    const float* bn1_b  = (const float*)d_in[8];
    const float* w2     = (const float*)d_in[9];
    const float* b2     = (const float*)d_in[10];
    const float* gbn_g  = (const float*)d_in[11];
    const float* gbn_b  = (const float*)d_in[12];
    const float* gcn_w  = (const float*)d_in[13];
    const float* gcn_b  = (const float*)d_in[14];

    float* out = (float*)d_out;
    float* ws  = (float*)d_ws;

    // workspace layout (float units)
    float* P_part  = ws;                                   // 8,388,608
    float* qs_part = P_part + (size_t)KC * NSP * DCH;      // 65,536
    float* hA      = qs_part + (size_t)KC * NSP;           // 131,072
    float* hB      = hA + NSP * DCH;                       // 131,072
    float* dinvb   = hB + NSP * DCH;                       // 1,024
    short* htb     = (short*)(dinvb + NSP);                // 131,072 bf16
    short* w1t     = (short*)((float*)htb + 65536);        // 28,672 bf16
    short* w2t     = (short*)((float*)w1t + 14336);        // 16,384 bf16
    float* b1f     = (float*)w2t + 8192;                   // 128
    float* b2f     = b1f + 128;                            // 128
    // GCN partials overlay P_part (dead after reduce_h0)
    float* m1p     = P_part;
    // xfT lives in the (currently dead) d_out buffer
    short* xfT     = (short*)d_out;

    prep_w<<<112 + NSP, 256, 0, stream>>>(w1, b1, bn0_g, bn0_b, w2, b2,
                                          bn1_g, bn1_b, adj,
                                          w1t, w2t, b1f, b2f, dinvb);
    cnn_mfma<<<HWP / 256, 256, 0, stream>>>(x, w1t, b1f, w2t, b2f, xfT);
    pool_mfma<<<(NSP / 128) * KC, 256, 0, stream>>>(Q, xfT, P_part, qs_part);
    reduce_h0<<<(NSP * DCH / 4) / 256, 256, 0, stream>>>(P_part, qs_part, hA);

    const float* hcur = hA;
    float* hnext = hB;
    for (int i = 0; i < 3; ++i) {
        m1_k<<<dim3(NSP / 16, JC), 256, 0, stream>>>(adj, hcur, dinvb,
                                                     gbn_g + i * DCH, gbn_b + i * DCH, m1p);
        gcnw_k<<<NSP / 16, 256, 0, stream>>>(m1p, hcur, dinvb,
                                             gbn_g + i * DCH, gbn_b + i * DCH,
                                             gcn_w + (size_t)i * DCH * DCH,
                                             gcn_b + i * DCH, hnext, htb);
        const float* tmp = hcur;
        hcur = hnext;
        hnext = (float*)tmp;
    }

    out_mfma<<<HWP / 128, 256, 0, stream>>>(Q, htb, out);
}

// Round 16
// 259.238 us; speedup vs baseline: 1.2438x; 1.0090x over previous
//
#include <hip/hip_runtime.h>

#define HWP 65536
#define NSP 1024
#define DCH 128
#define KC  64          // pooling k-chunks (rows per chunk = 1024)
#define JC  16          // m1 j-chunks (64 j's per chunk)

typedef float f32x4 __attribute__((ext_vector_type(4)));
typedef short bf16x8 __attribute__((ext_vector_type(8)));
typedef short bf16x4 __attribute__((ext_vector_type(4)));

__device__ __forceinline__ float lrelu(float v) { return v > 0.f ? v : 0.01f * v; }

// native conversion -> compiler emits v_cvt_pk_bf16_f32 pairs
__device__ __forceinline__ short f2bf(float f) {
    __bf16 h = (__bf16)f;
    return __builtin_bit_cast(short, h);
}
// exact bf16 -> f32 (shift into high half)
__device__ __forceinline__ float bf2f(short s) {
    unsigned u = ((unsigned)(unsigned short)s) << 16;
    return __builtin_bit_cast(float, u);
}

// raw barrier without the __syncthreads vmcnt(0) drain
__device__ __forceinline__ void raw_barrier() {
    asm volatile("s_barrier" ::: "memory");
}

// ---------------------------------------------------------------------------
// prep_w (verified) + fused dinv (blocks >= 112 do adj rowsums; disjoint data)
// ---------------------------------------------------------------------------
__global__ __launch_bounds__(256) void prep_w(
    const float* __restrict__ w1, const float* __restrict__ b1,
    const float* __restrict__ bn0_g, const float* __restrict__ bn0_b,
    const float* __restrict__ w2, const float* __restrict__ b2,
    const float* __restrict__ bn1_g, const float* __restrict__ bn1_b,
    const float* __restrict__ adj,
    short* __restrict__ w1t, short* __restrict__ w2t,
    float* __restrict__ b1f, float* __restrict__ b2f,
    float* __restrict__ dinv)
{
    if (blockIdx.x >= 112) {   // dinv part: one block per superpixel row
        __shared__ float red[256];
        const int n = blockIdx.x - 112;
        const int tt = threadIdx.x;
        float4 v = *(const float4*)&adj[(size_t)n * NSP + tt * 4];
        red[tt] = v.x + v.y + v.z + v.w;
        __syncthreads();
        for (int off = 128; off > 0; off >>= 1) {
            if (tt < off) red[tt] += red[tt + off];
            __syncthreads();
        }
        if (tt == 0) dinv[n] = rsqrtf(red[0] + 1.0f);
        return;
    }
    int t = blockIdx.x * 256 + threadIdx.x;
    if (t < 7 * 8 * 64 * 8) {
        int j = t & 7, lane = (t >> 3) & 63, nf = (t >> 9) & 7, ks = t >> 12;
        int ch = ks * 32 + (lane >> 4) * 8 + j;
        int d  = nf * 16 + (lane & 15);
        float v = (ch < 200) ? bn0_g[ch] * w1[ch * 128 + d] : 0.f;
        w1t[t] = f2bf(v);
    }
    if (t < 4 * 8 * 64 * 8) {
        int j = t & 7, lane = (t >> 3) & 63, nf = (t >> 9) & 7, ks = t >> 12;
        int k = ks * 32 + (lane >> 4) * 8 + j;
        int d = nf * 16 + (lane & 15);
        w2t[t] = f2bf(bn1_g[k] * w2[k * 128 + d]);
    }
    if (t < 128) {
        float s1 = b1[t], s2 = b2[t];
        for (int ch = 0; ch < 200; ++ch) s1 += bn0_b[ch] * w1[ch * 128 + t];
        for (int k = 0; k < 128; ++k)   s2 += bn1_b[k] * w2[k * 128 + t];
        b1f[t] = s1; b2f[t] = s2;
    }
}

// ---------------------------------------------------------------------------
// cnn_mfma (round-12 verified): 4 waves/block, xfT[d][pix] bf16
// ---------------------------------------------------------------------------
__global__ __launch_bounds__(256) void cnn_mfma(
    const float* __restrict__ x, const short* __restrict__ w1t,
    const float* __restrict__ b1f, const short* __restrict__ w2t,
    const float* __restrict__ b2f, short* __restrict__ xfT)
{
    __shared__ __align__(16) short a2[4][4][4][64][8];   // 64 KB
    const int t = threadIdx.x;
    const int w = t >> 6, l = t & 63;
    const int q = l >> 4, li = l & 15;
    const int pix0 = blockIdx.x * 256 + w * 64;

    f32x4 acc[4][8];
#pragma unroll
    for (int nf = 0; nf < 8; ++nf) {
        float bv = b1f[nf * 16 + li];
#pragma unroll
        for (int mf = 0; mf < 4; ++mf) acc[mf][nf] = (f32x4){bv, bv, bv, bv};
    }

    for (int ks = 0; ks < 7; ++ks) {
        bf16x8 a[4];
        if (ks < 6 || q == 0) {
            int k0 = ks * 32 + q * 8;
#pragma unroll
            for (int mf = 0; mf < 4; ++mf) {
                const float* sp = &x[(size_t)(pix0 + mf * 16 + li) * 200 + k0];
                float4 u = *(const float4*)sp;
                float4 v = *(const float4*)(sp + 4);
                a[mf][0] = f2bf(u.x); a[mf][1] = f2bf(u.y);
                a[mf][2] = f2bf(u.z); a[mf][3] = f2bf(u.w);
                a[mf][4] = f2bf(v.x); a[mf][5] = f2bf(v.y);
                a[mf][6] = f2bf(v.z); a[mf][7] = f2bf(v.w);
            }
        } else {
#pragma unroll
            for (int mf = 0; mf < 4; ++mf)
#pragma unroll
                for (int j = 0; j < 8; ++j) a[mf][j] = 0;
        }
#pragma unroll
        for (int nf = 0; nf < 8; ++nf) {
            bf16x8 b = *(const bf16x8*)&w1t[((ks * 8 + nf) * 64 + l) * 8];
#pragma unroll
            for (int mf = 0; mf < 4; ++mf)
                acc[mf][nf] = __builtin_amdgcn_mfma_f32_16x16x32_bf16(a[mf], b, acc[mf][nf], 0, 0, 0);
        }
    }

#pragma unroll
    for (int mf = 0; mf < 4; ++mf)
#pragma unroll
        for (int nf = 0; nf < 8; ++nf)
#pragma unroll
            for (int j = 0; j < 4; ++j) {
                float v = lrelu(acc[mf][nf][j]);
                int row = mf * 16 + q * 4 + j;
                int col = nf * 16 + li;
                int ks2 = col >> 5;
                int lane2 = (row & 15) + (((col & 31) >> 3) << 4);
                a2[w][ks2][mf][lane2][col & 7] = f2bf(v);
            }
    __syncthreads();

    f32x4 acc2[4][8];
#pragma unroll
    for (int nf = 0; nf < 8; ++nf) {
        float bv = b2f[nf * 16 + li];
#pragma unroll
        for (int mf = 0; mf < 4; ++mf) acc2[mf][nf] = (f32x4){bv, bv, bv, bv};
    }
#pragma unroll
    for (int ks = 0; ks < 4; ++ks) {
        bf16x8 a[4];
#pragma unroll
        for (int mf = 0; mf < 4; ++mf)
            a[mf] = *(const bf16x8*)&a2[w][ks][mf][l][0];
#pragma unroll
        for (int nf = 0; nf < 8; ++nf) {
            bf16x8 b = *(const bf16x8*)&w2t[((ks * 8 + nf) * 64 + l) * 8];
#pragma unroll
            for (int mf = 0; mf < 4; ++mf)
                acc2[mf][nf] = __builtin_amdgcn_mfma_f32_16x16x32_bf16(a[mf], b, acc2[mf][nf], 0, 0, 0);
        }
    }

#pragma unroll
    for (int mf = 0; mf < 4; ++mf)
#pragma unroll
        for (int nf = 0; nf < 8; ++nf) {
            bf16x4 p;
#pragma unroll
            for (int j = 0; j < 4; ++j) p[j] = f2bf(lrelu(acc2[mf][nf][j]));
            int d2 = nf * 16 + li;
            int pix = pix0 + mf * 16 + q * 4;
            *(bf16x4*)&xfT[(size_t)d2 * HWP + pix] = p;
        }
}

// ---------------------------------------------------------------------------
// pool_mfma (round-15 verified, + P_part now bf16)
// ---------------------------------------------------------------------------
__device__ __forceinline__ void pool_loadB(bf16x8 (&dst)[4], const short* __restrict__ xfT,
                                           int dcol0, int rbase)
{
#pragma unroll
    for (int nf = 0; nf < 4; ++nf)
        dst[nf] = *(const bf16x8*)&xfT[(size_t)(dcol0 + nf * 16) * HWP + rbase];
}

__device__ __forceinline__ void pool_stage(const float* __restrict__ Q, float* dst,
                                           int r0t, int n0blk, int wid, int l)
{
#pragma unroll
    for (int i = 0; i < 8; ++i) {
        int o = (i * 4 + wid) * 1024 + l * 16;     // byte offset in 32KB tile
        int row = o >> 9;                          // 512B per row (128 fp32)
        int wrd = (o & 511) >> 2;                  // word-in-row 0..127
        const float* src = Q + (size_t)(r0t + row) * NSP + n0blk
                             + (wrd ^ (((row >> 3) & 3) << 4));
        __builtin_amdgcn_global_load_lds(
            (const __attribute__((address_space(1))) unsigned int*)src,
            (__attribute__((address_space(3))) unsigned int*)(dst + (o >> 2)),
            16, 0, 0);
    }
}

__global__ __launch_bounds__(256, 2) void pool_mfma(
    const float* __restrict__ Q, const short* __restrict__ xfT,
    short* __restrict__ P_part, float* __restrict__ qs_part)
{
    __shared__ __align__(16) float qtile[2][8192];   // 2 x 32KB
    const int t = threadIdx.x;
    const int wid = t >> 6, l = t & 63;
    const int q = l >> 4, li = l & 15;
    const int nw = (wid >> 1) * 64;
    const int d0 = (wid & 1) * 64;
    // XCD swizzle: bid%8 = XCD (observed round-robin); give XCD k chunks 8k..8k+7
    const int bid   = blockIdx.x;          // 0..511
    const int xcd   = bid & 7;
    const int local = bid >> 3;            // 0..63
    const int n0blk = (local & 7) * 128;
    const int chunk = (local >> 3) | (xcd << 3);
    const int r0 = chunk * 1024;
    const int dcol0 = d0 + li;

    f32x4 acc[4][4];
    f32x4 accq[4];
#pragma unroll
    for (int mf = 0; mf < 4; ++mf) {
        accq[mf] = (f32x4){0.f, 0.f, 0.f, 0.f};
#pragma unroll
        for (int nf = 0; nf < 4; ++nf) acc[mf][nf] = (f32x4){0.f, 0.f, 0.f, 0.f};
    }
    bf16x8 bone;
    {
        short onev = (li == 0) ? (short)0x3F80 : (short)0;
#pragma unroll
        for (int j = 0; j < 8; ++j) bone[j] = onev;
    }

    // prologue: B(t0) + stage(t0)   [16 vmem ops in flight]
    bf16x8 bA[4], bB[4];
    pool_loadB(bA, xfT, dcol0, r0 + q * 8);
    pool_loadB(bB, xfT, dcol0, r0 + 32 + q * 8);
    pool_stage(Q, qtile[0], r0, n0blk, wid, l);

    for (int tile = 0; tile < 16; ++tile) {
        const int cur = tile & 1;
        raw_barrier();                               // prev compute's reads done
        bf16x8 nA[4], nB[4];
        if (tile < 15) {
            pool_loadB(nA, xfT, dcol0, r0 + (tile + 1) * 64 + q * 8);
            pool_loadB(nB, xfT, dcol0, r0 + (tile + 1) * 64 + 32 + q * 8);
            pool_stage(Q, qtile[cur ^ 1], r0 + (tile + 1) * 64, n0blk, wid, l);
            asm volatile("s_waitcnt vmcnt(16)" ::: "memory");   // tile-t ops done
        } else {
            asm volatile("s_waitcnt vmcnt(0)" ::: "memory");
        }
        raw_barrier();                               // stage(tile) visible
        __builtin_amdgcn_sched_barrier(0);
#pragma unroll
        for (int ks = 0; ks < 2; ++ks) {
            bf16x8 abf[4];
#pragma unroll
            for (int mf = 0; mf < 4; ++mf) {
#pragma unroll
                for (int j = 0; j < 8; ++j) {
                    int row = ks * 32 + q * 8 + j;           // (row>>3)&3 == q
                    int w2i = (nw + mf * 16 + li) ^ (q << 4);
                    abf[mf][j] = f2bf(qtile[cur][(row << 7) + w2i]);
                }
            }
#pragma unroll
            for (int mf = 0; mf < 4; ++mf) {
#pragma unroll
                for (int nf = 0; nf < 4; ++nf)
                    acc[mf][nf] = __builtin_amdgcn_mfma_f32_16x16x32_bf16(
                        abf[mf], (ks == 0) ? bA[nf] : bB[nf], acc[mf][nf], 0, 0, 0);
                if (d0 == 0)
                    accq[mf] = __builtin_amdgcn_mfma_f32_16x16x32_bf16(
                        abf[mf], bone, accq[mf], 0, 0, 0);
            }
        }
        if (tile < 15) {
#pragma unroll
            for (int nf = 0; nf < 4; ++nf) { bA[nf] = nA[nf]; bB[nf] = nB[nf]; }
        }
    }

#pragma unroll
    for (int mf = 0; mf < 4; ++mf)
#pragma unroll
        for (int nf = 0; nf < 4; ++nf)
#pragma unroll
            for (int j = 0; j < 4; ++j) {
                int n = n0blk + nw + mf * 16 + q * 4 + j;
                int d = d0 + nf * 16 + li;
                P_part[((size_t)chunk * NSP + n) * DCH + d] = f2bf(acc[mf][nf][j]);
            }
    if (d0 == 0 && li == 0)
#pragma unroll
        for (int mf = 0; mf < 4; ++mf)
#pragma unroll
            for (int j = 0; j < 4; ++j)
                qs_part[chunk * NSP + n0blk + nw + mf * 16 + q * 4 + j] = accq[mf][j];
}

// ---------------------------------------------------------------------------
// reduce_h0: bf16 partials, coalesced short8 loads; fp32 accumulate + divide
// thread handles 8 consecutive d of one n; grid 64 blocks.
// ---------------------------------------------------------------------------
__global__ __launch_bounds__(256) void reduce_h0(
    const short* __restrict__ P_part, const float* __restrict__ qs_part,
    float* __restrict__ h)
{
    const int idx8 = blockIdx.x * 256 + threadIdx.x;   // 0..16383 (8-elem groups)
    const int n = idx8 >> 4;
    float s[8];
#pragma unroll
    for (int j = 0; j < 8; ++j) s[j] = 0.f;
    for (int k = 0; k < KC; ++k) {
        bf16x8 v = *(const bf16x8*)&P_part[(size_t)k * (NSP * DCH) + idx8 * 8];
#pragma unroll
        for (int j = 0; j < 8; ++j) s[j] += bf2f(v[j]);
    }
    float qs = 0.f;
    for (int k = 0; k < KC; ++k) qs += qs_part[k * NSP + n];
    float inv = 1.f / qs;
    f32x4 o0 = (f32x4){s[0] * inv, s[1] * inv, s[2] * inv, s[3] * inv};
    f32x4 o1 = (f32x4){s[4] * inv, s[5] * inv, s[6] * inv, s[7] * inv};
    ((f32x4*)h)[idx8 * 2]     = o0;
    ((f32x4*)h)[idx8 * 2 + 1] = o1;
}

// ---------------------------------------------------------------------------
// m1_k (verified): grid (64 r-tiles, 16 j-chunks of 64)
// ---------------------------------------------------------------------------
__global__ __launch_bounds__(256) void m1_k(
    const float* __restrict__ adj, const float* __restrict__ h,
    const float* __restrict__ dinv, const float* __restrict__ gg,
    const float* __restrict__ gb, float* __restrict__ m1p)
{
    __shared__ float adjL[16][64];
    __shared__ float hbL[64][128];
    const int r0 = blockIdx.x * 16;
    const int jc = blockIdx.y;
    const int j0 = jc * 64;
    const int t = threadIdx.x;
    const int d = t & 127, ph = t >> 7;

    for (int i = t; i < 16 * 64; i += 256) {
        int row = i >> 6, col = i & 63;
        adjL[row][col] = adj[(size_t)(r0 + row) * NSP + j0 + col];
    }
    for (int i = t; i < 64 * 128; i += 256) {
        int jr = i >> 7, dd = i & 127;
        int j = j0 + jr;
        hbL[jr][dd] = dinv[j] * (gg[dd] * h[(size_t)j * DCH + dd] + gb[dd]);
    }
    __syncthreads();

    float acc[8];
#pragma unroll
    for (int pp = 0; pp < 8; ++pp) acc[pp] = 0.f;
    for (int jj = 0; jj < 64; ++jj) {
        float hv = hbL[jj][d];
#pragma unroll
        for (int pp = 0; pp < 8; ++pp)
            acc[pp] += adjL[ph * 8 + pp][jj] * hv;
    }
#pragma unroll
    for (int pp = 0; pp < 8; ++pp)
        m1p[(size_t)jc * (NSP * DCH) + (size_t)(r0 + ph * 8 + pp) * DCH + d] = acc[pp];
}

// ---------------------------------------------------------------------------
// gcnw_k (verified) + fused htb write
// ---------------------------------------------------------------------------
__global__ __launch_bounds__(256) void gcnw_k(
    const float* __restrict__ m1p, const float* __restrict__ h,
    const float* __restrict__ dinv, const float* __restrict__ gg,
    const float* __restrict__ gb, const float* __restrict__ W,
    const float* __restrict__ bias, float* __restrict__ hout,
    short* __restrict__ htb)
{
    __shared__ float ms[16 * 128];
    __shared__ float WL[64 * 128];
    const int r0 = blockIdx.x * 16;
    const int t = threadIdx.x;
    for (int i = t; i < 2048; i += 256) {
        int r = r0 + (i >> 7), dd = i & 127;
        float hbr = dinv[r] * (gg[dd] * h[(size_t)r * DCH + dd] + gb[dd]);
        float s = hbr;
#pragma unroll
        for (int kc = 0; kc < JC; ++kc)
            s += m1p[(size_t)kc * (NSP * DCH) + (size_t)r0 * DCH + i];
        ms[i] = dinv[r] * s;
    }
    const int e = t & 127, ph = t >> 7;
    float acc[8];
#pragma unroll
    for (int pp = 0; pp < 8; ++pp) acc[pp] = bias[e];
    for (int sub = 0; sub < 2; ++sub) {
        __syncthreads();
        for (int i = t; i < 64 * 128; i += 256)
            WL[i] = W[(size_t)sub * 64 * 128 + i];
        __syncthreads();
        for (int dd = 0; dd < 64; ++dd) {
            float wv = WL[dd * 128 + e];
#pragma unroll
            for (int pp = 0; pp < 8; ++pp)
                acc[pp] += ms[(ph * 8 + pp) * 128 + sub * 64 + dd] * wv;
        }
    }
#pragma unroll
    for (int pp = 0; pp < 8; ++pp) {
        int r = r0 + ph * 8 + pp;
        float v = lrelu(acc[pp]);
        hout[(size_t)r * DCH + e] = v;
        int lane = (((r >> 3) & 3) << 4) + (e & 15);
        htb[(((r >> 5) * 8 + (e >> 4)) * 64 + lane) * 8 + (r & 7)] = f2bf(v);
    }
}

// ---------------------------------------------------------------------------
// out_mfma (round-10/12 verified): LDS-staged + counted-vmcnt pipeline.
// ---------------------------------------------------------------------------
__device__ __forceinline__ void out_loadB(bf16x8 (&dst)[4], const short* __restrict__ htb,
                                          int ks, int nfbase, int l)
{
#pragma unroll
    for (int nf = 0; nf < 4; ++nf)
        dst[nf] = *(const bf16x8*)&htb[((ks * 8 + nfbase + nf) * 64 + l) * 8];
}

__device__ __forceinline__ void stage_q(const float* __restrict__ Q, float* dst,
                                        int r0, int kbase, int wid, int l)
{
#pragma unroll
    for (int i = 0; i < 8; ++i) {
        int o = (i * 4 + wid) * 1024 + l * 16;      // byte offset in 32KB tile
        int row = o >> 8;                           // 256B per row (64 fp32)
        int bin = o & 255;                          // 16B-aligned
        const float* src = Q + (size_t)(r0 + row) * NSP + kbase
                             + ((bin ^ ((row & 7) << 5)) >> 2);
        __builtin_amdgcn_global_load_lds(
            (const __attribute__((address_space(1))) unsigned int*)src,
            (__attribute__((address_space(3))) unsigned int*)(dst + (o >> 2)),
            16, 0, 0);
    }
}

__global__ __launch_bounds__(256, 2) void out_mfma(
    const float* __restrict__ Q, const short* __restrict__ htb,
    float* __restrict__ out)
{
    __shared__ __align__(16) float qs[2][8192];     // 2 x 32KB
    const int t = threadIdx.x;
    const int wid = t >> 6, l = t & 63;
    const int q = l >> 4, li = l & 15;
    const int r0 = blockIdx.x * 128;
    const int rw = (wid >> 1) * 64;
    const int d0 = (wid & 1) * 64;
    const int nfb = d0 >> 4;

    f32x4 acc[4][4];
#pragma unroll
    for (int mf = 0; mf < 4; ++mf)
#pragma unroll
        for (int nf = 0; nf < 4; ++nf) acc[mf][nf] = (f32x4){0.f, 0.f, 0.f, 0.f};

    bf16x8 bA[4], bB[4];
    out_loadB(bA, htb, 0, nfb, l);
    out_loadB(bB, htb, 1, nfb, l);
    stage_q(Q, qs[0], r0, 0, wid, l);

    for (int tile = 0; tile < 16; ++tile) {
        const int cur = tile & 1;
        raw_barrier();                               // prev compute's reads done
        bf16x8 nA[4], nB[4];
        if (tile < 15) {
            out_loadB(nA, htb, (tile + 1) * 2,     nfb, l);
            out_loadB(nB, htb, (tile + 1) * 2 + 1, nfb, l);
            stage_q(Q, qs[cur ^ 1], r0, (tile + 1) * 64, wid, l);
            asm volatile("s_waitcnt vmcnt(16)" ::: "memory");
        } else {
            asm volatile("s_waitcnt vmcnt(0)" ::: "memory");
        }
        raw_barrier();                               // stage(tile) visible
        __builtin_amdgcn_sched_barrier(0);
#pragma unroll
        for (int ks = 0; ks < 2; ++ks) {
            bf16x8 abf[4];
#pragma unroll
            for (int mf = 0; mf < 4; ++mf) {
                int rl = rw + mf * 16 + li;
                int koff = (ks * 32 + q * 8) << 2;
                const float* p = &qs[cur][(rl << 6) + ((koff ^ ((rl & 7) << 5)) >> 2)];
                float4 u = *(const float4*)p;
                float4 v = *(const float4*)(p + 4);
                abf[mf][0] = f2bf(u.x); abf[mf][1] = f2bf(u.y);
                abf[mf][2] = f2bf(u.z); abf[mf][3] = f2bf(u.w);
                abf[mf][4] = f2bf(v.x); abf[mf][5] = f2bf(v.y);
                abf[mf][6] = f2bf(v.z); abf[mf][7] = f2bf(v.w);
            }
            if (ks == 0) {
#pragma unroll
                for (int mf = 0; mf < 4; ++mf)
#pragma unroll
                    for (int nf = 0; nf < 4; ++nf)
                        acc[mf][nf] = __builtin_amdgcn_mfma_f32_16x16x32_bf16(abf[mf], bA[nf], acc[mf][nf], 0, 0, 0);
            } else {
#pragma unroll
                for (int mf = 0; mf < 4; ++mf)
#pragma unroll
                    for (int nf = 0; nf < 4; ++nf)
                        acc[mf][nf] = __builtin_amdgcn_mfma_f32_16x16x32_bf16(abf[mf], bB[nf], acc[mf][nf], 0, 0, 0);
            }
        }
        if (tile < 15) {
#pragma unroll
            for (int nf = 0; nf < 4; ++nf) { bA[nf] = nA[nf]; bB[nf] = nB[nf]; }
        }
    }

#pragma unroll
    for (int mf = 0; mf < 4; ++mf)
#pragma unroll
        for (int nf = 0; nf < 4; ++nf)
#pragma unroll
            for (int j = 0; j < 4; ++j)
                out[(size_t)(r0 + rw + mf * 16 + q * 4 + j) * DCH + d0 + nf * 16 + li] = acc[mf][nf][j];
}

// ---------------------------------------------------------------------------
extern "C" void kernel_launch(void* const* d_in, const int* in_sizes, int n_in,
                              void* d_out, int out_size, void* d_ws, size_t ws_size,
                              hipStream_t stream)
{
    const float* x      = (const float*)d_in[0];
    const float* Q      = (const float*)d_in[1];
    const float* adj    = (const float*)d_in[2];
    const float* bn0_g  = (const float*)d_in[3];
    const float* bn0_b  = (const float*)d_in[4];
    const float* w1     = (const float*)d_in[5];
    const float* b1     = (const float*)d_in[6];
    const float* bn1_g  = (const float*)d_in[7];
    const float* bn1_b  = (const float*)d_in[8];
    const float* w2     = (const float*)d_in[9];
    const float* b2     = (const float*)d_in[10];
    const float* gbn_g  = (const float*)d_in[11];
    const float* gbn_b  = (const float*)d_in[12];
    const float* gcn_w  = (const float*)d_in[13];
    const float* gcn_b  = (const float*)d_in[14];

    float* out = (float*)d_out;
    float* ws  = (float*)d_ws;

    // workspace layout (float units; P_part region reused as bf16 buffer)
    float* P_reg   = ws;                                   // 8,388,608 f region
    float* qs_part = P_reg + (size_t)KC * NSP * DCH;       // 65,536
    float* hA      = qs_part + (size_t)KC * NSP;           // 131,072
    float* hB      = hA + NSP * DCH;                       // 131,072
    float* dinvb   = hB + NSP * DCH;                       // 1,024
    short* htb     = (short*)(dinvb + NSP);                // 131,072 bf16
    short* w1t     = (short*)((float*)htb + 65536);        // 28,672 bf16
    short* w2t     = (short*)((float*)w1t + 14336);        // 16,384 bf16
    float* b1f     = (float*)w2t + 8192;                   // 128
    float* b2f     = b1f + 128;                            // 128
    short* P_part  = (short*)P_reg;                        // KC*NSP*DCH bf16
    // GCN partials overlay P_reg (dead after reduce_h0)
    float* m1p     = P_reg;
    // xfT lives in the (currently dead) d_out buffer
    short* xfT     = (short*)d_out;

    prep_w<<<112 + NSP, 256, 0, stream>>>(w1, b1, bn0_g, bn0_b, w2, b2,
                                          bn1_g, bn1_b, adj,
                                          w1t, w2t, b1f, b2f, dinvb);
    cnn_mfma<<<HWP / 256, 256, 0, stream>>>(x, w1t, b1f, w2t, b2f, xfT);
    pool_mfma<<<(NSP / 128) * KC, 256, 0, stream>>>(Q, xfT, P_part, qs_part);
    reduce_h0<<<(NSP * DCH / 8) / 256, 256, 0, stream>>>(P_part, qs_part, hA);

    const float* hcur = hA;
    float* hnext = hB;
    for (int i = 0; i < 3; ++i) {
        m1_k<<<dim3(NSP / 16, JC), 256, 0, stream>>>(adj, hcur, dinvb,
                                                     gbn_g + i * DCH, gbn_b + i * DCH, m1p);
        gcnw_k<<<NSP / 16, 256, 0, stream>>>(m1p, hcur, dinvb,
                                             gbn_g + i * DCH, gbn_b + i * DCH,
                                             gcn_w + (size_t)i * DCH * DCH,
                                             gcn_b + i * DCH, hnext, htb);
        const float* tmp = hcur;
        hcur = hnext;
        hnext = (float*)tmp;
    }

    out_mfma<<<HWP / 128, 256, 0, stream>>>(Q, htb, out);
}

// Round 17
// 257.609 us; speedup vs baseline: 1.2516x; 1.0063x over previous
//
#include <hip/hip_runtime.h>

#define HWP 65536
#define NSP 1024
#define DCH 128
#define KC  64          // pooling k-chunks (rows per chunk = 1024)
#define JC  16          // m1 j-chunks (64 j's per chunk)

typedef float f32x4 __attribute__((ext_vector_type(4)));
typedef short bf16x8 __attribute__((ext_vector_type(8)));
typedef short bf16x4 __attribute__((ext_vector_type(4)));

__device__ __forceinline__ float lrelu(float v) { return v > 0.f ? v : 0.01f * v; }

// native conversion -> compiler emits v_cvt_pk_bf16_f32 pairs
__device__ __forceinline__ short f2bf(float f) {
    __bf16 h = (__bf16)f;
    return __builtin_bit_cast(short, h);
}
// exact bf16 -> f32 (shift into high half)
__device__ __forceinline__ float bf2f(short s) {
    unsigned u = ((unsigned)(unsigned short)s) << 16;
    return __builtin_bit_cast(float, u);
}

// raw barrier without the __syncthreads vmcnt(0) drain
__device__ __forceinline__ void raw_barrier() {
    asm volatile("s_barrier" ::: "memory");
}

// ---------------------------------------------------------------------------
// prep_w (verified) + fused dinv (blocks >= 112 do adj rowsums; disjoint data)
// ---------------------------------------------------------------------------
__global__ __launch_bounds__(256) void prep_w(
    const float* __restrict__ w1, const float* __restrict__ b1,
    const float* __restrict__ bn0_g, const float* __restrict__ bn0_b,
    const float* __restrict__ w2, const float* __restrict__ b2,
    const float* __restrict__ bn1_g, const float* __restrict__ bn1_b,
    const float* __restrict__ adj,
    short* __restrict__ w1t, short* __restrict__ w2t,
    float* __restrict__ b1f, float* __restrict__ b2f,
    float* __restrict__ dinv)
{
    if (blockIdx.x >= 112) {   // dinv part: one block per superpixel row
        __shared__ float red[256];
        const int n = blockIdx.x - 112;
        const int tt = threadIdx.x;
        float4 v = *(const float4*)&adj[(size_t)n * NSP + tt * 4];
        red[tt] = v.x + v.y + v.z + v.w;
        __syncthreads();
        for (int off = 128; off > 0; off >>= 1) {
            if (tt < off) red[tt] += red[tt + off];
            __syncthreads();
        }
        if (tt == 0) dinv[n] = rsqrtf(red[0] + 1.0f);
        return;
    }
    int t = blockIdx.x * 256 + threadIdx.x;
    if (t < 7 * 8 * 64 * 8) {
        int j = t & 7, lane = (t >> 3) & 63, nf = (t >> 9) & 7, ks = t >> 12;
        int ch = ks * 32 + (lane >> 4) * 8 + j;
        int d  = nf * 16 + (lane & 15);
        float v = (ch < 200) ? bn0_g[ch] * w1[ch * 128 + d] : 0.f;
        w1t[t] = f2bf(v);
    }
    if (t < 4 * 8 * 64 * 8) {
        int j = t & 7, lane = (t >> 3) & 63, nf = (t >> 9) & 7, ks = t >> 12;
        int k = ks * 32 + (lane >> 4) * 8 + j;
        int d = nf * 16 + (lane & 15);
        w2t[t] = f2bf(bn1_g[k] * w2[k * 128 + d]);
    }
    if (t < 128) {
        float s1 = b1[t], s2 = b2[t];
        for (int ch = 0; ch < 200; ++ch) s1 += bn0_b[ch] * w1[ch * 128 + t];
        for (int k = 0; k < 128; ++k)   s2 += bn1_b[k] * w2[k * 128 + t];
        b1f[t] = s1; b2f[t] = s2;
    }
}

// ---------------------------------------------------------------------------
// cnn_mfma (round-12 verified): 4 waves/block, xfT[d][pix] bf16
// ---------------------------------------------------------------------------
__global__ __launch_bounds__(256) void cnn_mfma(
    const float* __restrict__ x, const short* __restrict__ w1t,
    const float* __restrict__ b1f, const short* __restrict__ w2t,
    const float* __restrict__ b2f, short* __restrict__ xfT)
{
    __shared__ __align__(16) short a2[4][4][4][64][8];   // 64 KB
    const int t = threadIdx.x;
    const int w = t >> 6, l = t & 63;
    const int q = l >> 4, li = l & 15;
    const int pix0 = blockIdx.x * 256 + w * 64;

    f32x4 acc[4][8];
#pragma unroll
    for (int nf = 0; nf < 8; ++nf) {
        float bv = b1f[nf * 16 + li];
#pragma unroll
        for (int mf = 0; mf < 4; ++mf) acc[mf][nf] = (f32x4){bv, bv, bv, bv};
    }

    for (int ks = 0; ks < 7; ++ks) {
        bf16x8 a[4];
        if (ks < 6 || q == 0) {
            int k0 = ks * 32 + q * 8;
#pragma unroll
            for (int mf = 0; mf < 4; ++mf) {
                const float* sp = &x[(size_t)(pix0 + mf * 16 + li) * 200 + k0];
                float4 u = *(const float4*)sp;
                float4 v = *(const float4*)(sp + 4);
                a[mf][0] = f2bf(u.x); a[mf][1] = f2bf(u.y);
                a[mf][2] = f2bf(u.z); a[mf][3] = f2bf(u.w);
                a[mf][4] = f2bf(v.x); a[mf][5] = f2bf(v.y);
                a[mf][6] = f2bf(v.z); a[mf][7] = f2bf(v.w);
            }
        } else {
#pragma unroll
            for (int mf = 0; mf < 4; ++mf)
#pragma unroll
                for (int j = 0; j < 8; ++j) a[mf][j] = 0;
        }
#pragma unroll
        for (int nf = 0; nf < 8; ++nf) {
            bf16x8 b = *(const bf16x8*)&w1t[((ks * 8 + nf) * 64 + l) * 8];
#pragma unroll
            for (int mf = 0; mf < 4; ++mf)
                acc[mf][nf] = __builtin_amdgcn_mfma_f32_16x16x32_bf16(a[mf], b, acc[mf][nf], 0, 0, 0);
        }
    }

#pragma unroll
    for (int mf = 0; mf < 4; ++mf)
#pragma unroll
        for (int nf = 0; nf < 8; ++nf)
#pragma unroll
            for (int j = 0; j < 4; ++j) {
                float v = lrelu(acc[mf][nf][j]);
                int row = mf * 16 + q * 4 + j;
                int col = nf * 16 + li;
                int ks2 = col >> 5;
                int lane2 = (row & 15) + (((col & 31) >> 3) << 4);
                a2[w][ks2][mf][lane2][col & 7] = f2bf(v);
            }
    __syncthreads();

    f32x4 acc2[4][8];
#pragma unroll
    for (int nf = 0; nf < 8; ++nf) {
        float bv = b2f[nf * 16 + li];
#pragma unroll
        for (int mf = 0; mf < 4; ++mf) acc2[mf][nf] = (f32x4){bv, bv, bv, bv};
    }
#pragma unroll
    for (int ks = 0; ks < 4; ++ks) {
        bf16x8 a[4];
#pragma unroll
        for (int mf = 0; mf < 4; ++mf)
            a[mf] = *(const bf16x8*)&a2[w][ks][mf][l][0];
#pragma unroll
        for (int nf = 0; nf < 8; ++nf) {
            bf16x8 b = *(const bf16x8*)&w2t[((ks * 8 + nf) * 64 + l) * 8];
#pragma unroll
            for (int mf = 0; mf < 4; ++mf)
                acc2[mf][nf] = __builtin_amdgcn_mfma_f32_16x16x32_bf16(a[mf], b, acc2[mf][nf], 0, 0, 0);
        }
    }

#pragma unroll
    for (int mf = 0; mf < 4; ++mf)
#pragma unroll
        for (int nf = 0; nf < 8; ++nf) {
            bf16x4 p;
#pragma unroll
            for (int j = 0; j < 4; ++j) p[j] = f2bf(lrelu(acc2[mf][nf][j]));
            int d2 = nf * 16 + li;
            int pix = pix0 + mf * 16 + q * 4;
            *(bf16x4*)&xfT[(size_t)d2 * HWP + pix] = p;
        }
}

// ---------------------------------------------------------------------------
// pool_mfma (round-16 verified; sched_barrier removed — memory-clobber asm +
// register data-deps already enforce ordering)
// ---------------------------------------------------------------------------
__device__ __forceinline__ void pool_loadB(bf16x8 (&dst)[4], const short* __restrict__ xfT,
                                           int dcol0, int rbase)
{
#pragma unroll
    for (int nf = 0; nf < 4; ++nf)
        dst[nf] = *(const bf16x8*)&xfT[(size_t)(dcol0 + nf * 16) * HWP + rbase];
}

__device__ __forceinline__ void pool_stage(const float* __restrict__ Q, float* dst,
                                           int r0t, int n0blk, int wid, int l)
{
#pragma unroll
    for (int i = 0; i < 8; ++i) {
        int o = (i * 4 + wid) * 1024 + l * 16;     // byte offset in 32KB tile
        int row = o >> 9;                          // 512B per row (128 fp32)
        int wrd = (o & 511) >> 2;                  // word-in-row 0..127
        const float* src = Q + (size_t)(r0t + row) * NSP + n0blk
                             + (wrd ^ (((row >> 3) & 3) << 4));
        __builtin_amdgcn_global_load_lds(
            (const __attribute__((address_space(1))) unsigned int*)src,
            (__attribute__((address_space(3))) unsigned int*)(dst + (o >> 2)),
            16, 0, 0);
    }
}

__global__ __launch_bounds__(256, 2) void pool_mfma(
    const float* __restrict__ Q, const short* __restrict__ xfT,
    short* __restrict__ P_part, float* __restrict__ qs_part)
{
    __shared__ __align__(16) float qtile[2][8192];   // 2 x 32KB
    const int t = threadIdx.x;
    const int wid = t >> 6, l = t & 63;
    const int q = l >> 4, li = l & 15;
    const int nw = (wid >> 1) * 64;
    const int d0 = (wid & 1) * 64;
    // XCD swizzle: bid%8 = XCD (observed round-robin); give XCD k chunks 8k..8k+7
    const int bid   = blockIdx.x;          // 0..511
    const int xcd   = bid & 7;
    const int local = bid >> 3;            // 0..63
    const int n0blk = (local & 7) * 128;
    const int chunk = (local >> 3) | (xcd << 3);
    const int r0 = chunk * 1024;
    const int dcol0 = d0 + li;

    f32x4 acc[4][4];
    f32x4 accq[4];
#pragma unroll
    for (int mf = 0; mf < 4; ++mf) {
        accq[mf] = (f32x4){0.f, 0.f, 0.f, 0.f};
#pragma unroll
        for (int nf = 0; nf < 4; ++nf) acc[mf][nf] = (f32x4){0.f, 0.f, 0.f, 0.f};
    }
    bf16x8 bone;
    {
        short onev = (li == 0) ? (short)0x3F80 : (short)0;
#pragma unroll
        for (int j = 0; j < 8; ++j) bone[j] = onev;
    }

    // prologue: B(t0) + stage(t0)   [16 vmem ops in flight]
    bf16x8 bA[4], bB[4];
    pool_loadB(bA, xfT, dcol0, r0 + q * 8);
    pool_loadB(bB, xfT, dcol0, r0 + 32 + q * 8);
    pool_stage(Q, qtile[0], r0, n0blk, wid, l);

    for (int tile = 0; tile < 16; ++tile) {
        const int cur = tile & 1;
        raw_barrier();                               // prev compute's reads done
        bf16x8 nA[4], nB[4];
        if (tile < 15) {
            pool_loadB(nA, xfT, dcol0, r0 + (tile + 1) * 64 + q * 8);
            pool_loadB(nB, xfT, dcol0, r0 + (tile + 1) * 64 + 32 + q * 8);
            pool_stage(Q, qtile[cur ^ 1], r0 + (tile + 1) * 64, n0blk, wid, l);
            asm volatile("s_waitcnt vmcnt(16)" ::: "memory");   // tile-t ops done
        } else {
            asm volatile("s_waitcnt vmcnt(0)" ::: "memory");
        }
        raw_barrier();                               // stage(tile) visible
#pragma unroll
        for (int ks = 0; ks < 2; ++ks) {
            bf16x8 abf[4];
#pragma unroll
            for (int mf = 0; mf < 4; ++mf) {
#pragma unroll
                for (int j = 0; j < 8; ++j) {
                    int row = ks * 32 + q * 8 + j;           // (row>>3)&3 == q
                    int w2i = (nw + mf * 16 + li) ^ (q << 4);
                    abf[mf][j] = f2bf(qtile[cur][(row << 7) + w2i]);
                }
            }
#pragma unroll
            for (int mf = 0; mf < 4; ++mf) {
#pragma unroll
                for (int nf = 0; nf < 4; ++nf)
                    acc[mf][nf] = __builtin_amdgcn_mfma_f32_16x16x32_bf16(
                        abf[mf], (ks == 0) ? bA[nf] : bB[nf], acc[mf][nf], 0, 0, 0);
                if (d0 == 0)
                    accq[mf] = __builtin_amdgcn_mfma_f32_16x16x32_bf16(
                        abf[mf], bone, accq[mf], 0, 0, 0);
            }
        }
        if (tile < 15) {
#pragma unroll
            for (int nf = 0; nf < 4; ++nf) { bA[nf] = nA[nf]; bB[nf] = nB[nf]; }
        }
    }

#pragma unroll
    for (int mf = 0; mf < 4; ++mf)
#pragma unroll
        for (int nf = 0; nf < 4; ++nf)
#pragma unroll
            for (int j = 0; j < 4; ++j) {
                int n = n0blk + nw + mf * 16 + q * 4 + j;
                int d = d0 + nf * 16 + li;
                P_part[((size_t)chunk * NSP + n) * DCH + d] = f2bf(acc[mf][nf][j]);
            }
    if (d0 == 0 && li == 0)
#pragma unroll
        for (int mf = 0; mf < 4; ++mf)
#pragma unroll
            for (int j = 0; j < 4; ++j)
                qs_part[chunk * NSP + n0blk + nw + mf * 16 + q * 4 + j] = accq[mf][j];
}

// ---------------------------------------------------------------------------
// reduce_h0: bf16 partials, coalesced short8 loads; fp32 accumulate + divide
// ---------------------------------------------------------------------------
__global__ __launch_bounds__(256) void reduce_h0(
    const short* __restrict__ P_part, const float* __restrict__ qs_part,
    float* __restrict__ h)
{
    const int idx8 = blockIdx.x * 256 + threadIdx.x;   // 0..16383 (8-elem groups)
    const int n = idx8 >> 4;
    float s[8];
#pragma unroll
    for (int j = 0; j < 8; ++j) s[j] = 0.f;
    for (int k = 0; k < KC; ++k) {
        bf16x8 v = *(const bf16x8*)&P_part[(size_t)k * (NSP * DCH) + idx8 * 8];
#pragma unroll
        for (int j = 0; j < 8; ++j) s[j] += bf2f(v[j]);
    }
    float qs = 0.f;
    for (int k = 0; k < KC; ++k) qs += qs_part[k * NSP + n];
    float inv = 1.f / qs;
    f32x4 o0 = (f32x4){s[0] * inv, s[1] * inv, s[2] * inv, s[3] * inv};
    f32x4 o1 = (f32x4){s[4] * inv, s[5] * inv, s[6] * inv, s[7] * inv};
    ((f32x4*)h)[idx8 * 2]     = o0;
    ((f32x4*)h)[idx8 * 2 + 1] = o1;
}

// ---------------------------------------------------------------------------
// m1_k (verified): grid (64 r-tiles, 16 j-chunks of 64)
// ---------------------------------------------------------------------------
__global__ __launch_bounds__(256) void m1_k(
    const float* __restrict__ adj, const float* __restrict__ h,
    const float* __restrict__ dinv, const float* __restrict__ gg,
    const float* __restrict__ gb, float* __restrict__ m1p)
{
    __shared__ float adjL[16][64];
    __shared__ float hbL[64][128];
    const int r0 = blockIdx.x * 16;
    const int jc = blockIdx.y;
    const int j0 = jc * 64;
    const int t = threadIdx.x;
    const int d = t & 127, ph = t >> 7;

    for (int i = t; i < 16 * 64; i += 256) {
        int row = i >> 6, col = i & 63;
        adjL[row][col] = adj[(size_t)(r0 + row) * NSP + j0 + col];
    }
    for (int i = t; i < 64 * 128; i += 256) {
        int jr = i >> 7, dd = i & 127;
        int j = j0 + jr;
        hbL[jr][dd] = dinv[j] * (gg[dd] * h[(size_t)j * DCH + dd] + gb[dd]);
    }
    __syncthreads();

    float acc[8];
#pragma unroll
    for (int pp = 0; pp < 8; ++pp) acc[pp] = 0.f;
    for (int jj = 0; jj < 64; ++jj) {
        float hv = hbL[jj][d];
#pragma unroll
        for (int pp = 0; pp < 8; ++pp)
            acc[pp] += adjL[ph * 8 + pp][jj] * hv;
    }
#pragma unroll
    for (int pp = 0; pp < 8; ++pp)
        m1p[(size_t)jc * (NSP * DCH) + (size_t)(r0 + ph * 8 + pp) * DCH + d] = acc[pp];
}

// ---------------------------------------------------------------------------
// gcnw_k (verified) + fused htb write
// ---------------------------------------------------------------------------
__global__ __launch_bounds__(256) void gcnw_k(
    const float* __restrict__ m1p, const float* __restrict__ h,
    const float* __restrict__ dinv, const float* __restrict__ gg,
    const float* __restrict__ gb, const float* __restrict__ W,
    const float* __restrict__ bias, float* __restrict__ hout,
    short* __restrict__ htb)
{
    __shared__ float ms[16 * 128];
    __shared__ float WL[64 * 128];
    const int r0 = blockIdx.x * 16;
    const int t = threadIdx.x;
    for (int i = t; i < 2048; i += 256) {
        int r = r0 + (i >> 7), dd = i & 127;
        float hbr = dinv[r] * (gg[dd] * h[(size_t)r * DCH + dd] + gb[dd]);
        float s = hbr;
#pragma unroll
        for (int kc = 0; kc < JC; ++kc)
            s += m1p[(size_t)kc * (NSP * DCH) + (size_t)r0 * DCH + i];
        ms[i] = dinv[r] * s;
    }
    const int e = t & 127, ph = t >> 7;
    float acc[8];
#pragma unroll
    for (int pp = 0; pp < 8; ++pp) acc[pp] = bias[e];
    for (int sub = 0; sub < 2; ++sub) {
        __syncthreads();
        for (int i = t; i < 64 * 128; i += 256)
            WL[i] = W[(size_t)sub * 64 * 128 + i];
        __syncthreads();
        for (int dd = 0; dd < 64; ++dd) {
            float wv = WL[dd * 128 + e];
#pragma unroll
            for (int pp = 0; pp < 8; ++pp)
                acc[pp] += ms[(ph * 8 + pp) * 128 + sub * 64 + dd] * wv;
        }
    }
#pragma unroll
    for (int pp = 0; pp < 8; ++pp) {
        int r = r0 + ph * 8 + pp;
        float v = lrelu(acc[pp]);
        hout[(size_t)r * DCH + e] = v;
        int lane = (((r >> 3) & 3) << 4) + (e & 15);
        htb[(((r >> 5) * 8 + (e >> 4)) * 64 + lane) * 8 + (r & 7)] = f2bf(v);
    }
}

// ---------------------------------------------------------------------------
// out_mfma (round-16 verified; sched_barrier removed)
// ---------------------------------------------------------------------------
__device__ __forceinline__ void out_loadB(bf16x8 (&dst)[4], const short* __restrict__ htb,
                                          int ks, int nfbase, int l)
{
#pragma unroll
    for (int nf = 0; nf < 4; ++nf)
        dst[nf] = *(const bf16x8*)&htb[((ks * 8 + nfbase + nf) * 64 + l) * 8];
}

__device__ __forceinline__ void stage_q(const float* __restrict__ Q, float* dst,
                                        int r0, int kbase, int wid, int l)
{
#pragma unroll
    for (int i = 0; i < 8; ++i) {
        int o = (i * 4 + wid) * 1024 + l * 16;      // byte offset in 32KB tile
        int row = o >> 8;                           // 256B per row (64 fp32)
        int bin = o & 255;                          // 16B-aligned
        const float* src = Q + (size_t)(r0 + row) * NSP + kbase
                             + ((bin ^ ((row & 7) << 5)) >> 2);
        __builtin_amdgcn_global_load_lds(
            (const __attribute__((address_space(1))) unsigned int*)src,
            (__attribute__((address_space(3))) unsigned int*)(dst + (o >> 2)),
            16, 0, 0);
    }
}

__global__ __launch_bounds__(256, 2) void out_mfma(
    const float* __restrict__ Q, const short* __restrict__ htb,
    float* __restrict__ out)
{
    __shared__ __align__(16) float qs[2][8192];     // 2 x 32KB
    const int t = threadIdx.x;
    const int wid = t >> 6, l = t & 63;
    const int q = l >> 4, li = l & 15;
    const int r0 = blockIdx.x * 128;
    const int rw = (wid >> 1) * 64;
    const int d0 = (wid & 1) * 64;
    const int nfb = d0 >> 4;

    f32x4 acc[4][4];
#pragma unroll
    for (int mf = 0; mf < 4; ++mf)
#pragma unroll
        for (int nf = 0; nf < 4; ++nf) acc[mf][nf] = (f32x4){0.f, 0.f, 0.f, 0.f};

    bf16x8 bA[4], bB[4];
    out_loadB(bA, htb, 0, nfb, l);
    out_loadB(bB, htb, 1, nfb, l);
    stage_q(Q, qs[0], r0, 0, wid, l);

    for (int tile = 0; tile < 16; ++tile) {
        const int cur = tile & 1;
        raw_barrier();                               // prev compute's reads done
        bf16x8 nA[4], nB[4];
        if (tile < 15) {
            out_loadB(nA, htb, (tile + 1) * 2,     nfb, l);
            out_loadB(nB, htb, (tile + 1) * 2 + 1, nfb, l);
            stage_q(Q, qs[cur ^ 1], r0, (tile + 1) * 64, wid, l);
            asm volatile("s_waitcnt vmcnt(16)" ::: "memory");
        } else {
            asm volatile("s_waitcnt vmcnt(0)" ::: "memory");
        }
        raw_barrier();                               // stage(tile) visible
#pragma unroll
        for (int ks = 0; ks < 2; ++ks) {
            bf16x8 abf[4];
#pragma unroll
            for (int mf = 0; mf < 4; ++mf) {
                int rl = rw + mf * 16 + li;
                int koff = (ks * 32 + q * 8) << 2;
                const float* p = &qs[cur][(rl << 6) + ((koff ^ ((rl & 7) << 5)) >> 2)];
                float4 u = *(const float4*)p;
                float4 v = *(const float4*)(p + 4);
                abf[mf][0] = f2bf(u.x); abf[mf][1] = f2bf(u.y);
                abf[mf][2] = f2bf(u.z); abf[mf][3] = f2bf(u.w);
                abf[mf][4] = f2bf(v.x); abf[mf][5] = f2bf(v.y);
                abf[mf][6] = f2bf(v.z); abf[mf][7] = f2bf(v.w);
            }
            if (ks == 0) {
#pragma unroll
                for (int mf = 0; mf < 4; ++mf)
#pragma unroll
                    for (int nf = 0; nf < 4; ++nf)
                        acc[mf][nf] = __builtin_amdgcn_mfma_f32_16x16x32_bf16(abf[mf], bA[nf], acc[mf][nf], 0, 0, 0);
            } else {
#pragma unroll
                for (int mf = 0; mf < 4; ++mf)
#pragma unroll
                    for (int nf = 0; nf < 4; ++nf)
                        acc[mf][nf] = __builtin_amdgcn_mfma_f32_16x16x32_bf16(abf[mf], bB[nf], acc[mf][nf], 0, 0, 0);
            }
        }
        if (tile < 15) {
#pragma unroll
            for (int nf = 0; nf < 4; ++nf) { bA[nf] = nA[nf]; bB[nf] = nB[nf]; }
        }
    }

#pragma unroll
    for (int mf = 0; mf < 4; ++mf)
#pragma unroll
        for (int nf = 0; nf < 4; ++nf)
#pragma unroll
            for (int j = 0; j < 4; ++j)
                out[(size_t)(r0 + rw + mf * 16 + q * 4 + j) * DCH + d0 + nf * 16 + li] = acc[mf][nf][j];
}

// ---------------------------------------------------------------------------
extern "C" void kernel_launch(void* const* d_in, const int* in_sizes, int n_in,
                              void* d_out, int out_size, void* d_ws, size_t ws_size,
                              hipStream_t stream)
{
    const float* x      = (const float*)d_in[0];
    const float* Q      = (const float*)d_in[1];
    const float* adj    = (const float*)d_in[2];
    const float* bn0_g  = (const float*)d_in[3];
    const float* bn0_b  = (const float*)d_in[4];
    const float* w1     = (const float*)d_in[5];
    const float* b1     = (const float*)d_in[6];
    const float* bn1_g  = (const float*)d_in[7];
    const float* bn1_b  = (const float*)d_in[8];
    const float* w2     = (const float*)d_in[9];
    const float* b2     = (const float*)d_in[10];
    const float* gbn_g  = (const float*)d_in[11];
    const float* gbn_b  = (const float*)d_in[12];
    const float* gcn_w  = (const float*)d_in[13];
    const float* gcn_b  = (const float*)d_in[14];

    float* out = (float*)d_out;
    float* ws  = (float*)d_ws;

    // workspace layout (float units; P_part region reused as bf16 buffer)
    float* P_reg   = ws;                                   // 8,388,608 f region
    float* qs_part = P_reg + (size_t)KC * NSP * DCH;       // 65,536
    float* hA      = qs_part + (size_t)KC * NSP;           // 131,072
    float* hB      = hA + NSP * DCH;                       // 131,072
    float* dinvb   = hB + NSP * DCH;                       // 1,024
    short* htb     = (short*)(dinvb + NSP);                // 131,072 bf16
    short* w1t     = (short*)((float*)htb + 65536);        // 28,672 bf16
    short* w2t     = (short*)((float*)w1t + 14336);        // 16,384 bf16
    float* b1f     = (float*)w2t + 8192;                   // 128
    float* b2f     = b1f + 128;                            // 128
    short* P_part  = (short*)P_reg;                        // KC*NSP*DCH bf16
    // GCN partials overlay P_reg (dead after reduce_h0)
    float* m1p     = P_reg;
    // xfT lives in the (currently dead) d_out buffer
    short* xfT     = (short*)d_out;

    prep_w<<<112 + NSP, 256, 0, stream>>>(w1, b1, bn0_g, bn0_b, w2, b2,
                                          bn1_g, bn1_b, adj,
                                          w1t, w2t, b1f, b2f, dinvb);
    cnn_mfma<<<HWP / 256, 256, 0, stream>>>(x, w1t, b1f, w2t, b2f, xfT);
    pool_mfma<<<(NSP / 128) * KC, 256, 0, stream>>>(Q, xfT, P_part, qs_part);
    reduce_h0<<<(NSP * DCH / 8) / 256, 256, 0, stream>>>(P_part, qs_part, hA);

    const float* hcur = hA;
    float* hnext = hB;
    for (int i = 0; i < 3; ++i) {
        m1_k<<<dim3(NSP / 16, JC), 256, 0, stream>>>(adj, hcur, dinvb,
                                                     gbn_g + i * DCH, gbn_b + i * DCH, m1p);
        gcnw_k<<<NSP / 16, 256, 0, stream>>>(m1p, hcur, dinvb,
                                             gbn_g + i * DCH, gbn_b + i * DCH,
                                             gcn_w + (size_t)i * DCH * DCH,
                                             gcn_b + i * DCH, hnext, htb);
        const float* tmp = hcur;
        hcur = hnext;
        hnext = (float*)tmp;
    }

    out_mfma<<<HWP / 128, 256, 0, stream>>>(Q, htb, out);
}

// Round 18
// 254.614 us; speedup vs baseline: 1.2664x; 1.0118x over previous
//
#include <hip/hip_runtime.h>

#define HWP 65536
#define NSP 1024
#define DCH 128
#define KC  64          // pooling k-chunks (rows per chunk = 1024)
#define JC  16          // m1 j-chunks (64 j's per chunk)

typedef float f32x4 __attribute__((ext_vector_type(4)));
typedef short bf16x8 __attribute__((ext_vector_type(8)));
typedef short bf16x4 __attribute__((ext_vector_type(4)));

__device__ __forceinline__ float lrelu(float v) { return v > 0.f ? v : 0.01f * v; }

// native conversion -> compiler emits v_cvt_pk_bf16_f32 pairs
__device__ __forceinline__ short f2bf(float f) {
    __bf16 h = (__bf16)f;
    return __builtin_bit_cast(short, h);
}
// exact bf16 -> f32 (shift into high half)
__device__ __forceinline__ float bf2f(short s) {
    unsigned u = ((unsigned)(unsigned short)s) << 16;
    return __builtin_bit_cast(float, u);
}

// raw barrier without the __syncthreads vmcnt(0) drain
__device__ __forceinline__ void raw_barrier() {
    asm volatile("s_barrier" ::: "memory");
}

// ---------------------------------------------------------------------------
// prep_w (verified) + fused dinv (blocks >= 112 do adj rowsums; disjoint data)
// ---------------------------------------------------------------------------
__global__ __launch_bounds__(256) void prep_w(
    const float* __restrict__ w1, const float* __restrict__ b1,
    const float* __restrict__ bn0_g, const float* __restrict__ bn0_b,
    const float* __restrict__ w2, const float* __restrict__ b2,
    const float* __restrict__ bn1_g, const float* __restrict__ bn1_b,
    const float* __restrict__ adj,
    short* __restrict__ w1t, short* __restrict__ w2t,
    float* __restrict__ b1f, float* __restrict__ b2f,
    float* __restrict__ dinv)
{
    if (blockIdx.x >= 112) {   // dinv part: one block per superpixel row
        __shared__ float red[256];
        const int n = blockIdx.x - 112;
        const int tt = threadIdx.x;
        float4 v = *(const float4*)&adj[(size_t)n * NSP + tt * 4];
        red[tt] = v.x + v.y + v.z + v.w;
        __syncthreads();
        for (int off = 128; off > 0; off >>= 1) {
            if (tt < off) red[tt] += red[tt + off];
            __syncthreads();
        }
        if (tt == 0) dinv[n] = rsqrtf(red[0] + 1.0f);
        return;
    }
    int t = blockIdx.x * 256 + threadIdx.x;
    if (t < 7 * 8 * 64 * 8) {
        int j = t & 7, lane = (t >> 3) & 63, nf = (t >> 9) & 7, ks = t >> 12;
        int ch = ks * 32 + (lane >> 4) * 8 + j;
        int d  = nf * 16 + (lane & 15);
        float v = (ch < 200) ? bn0_g[ch] * w1[ch * 128 + d] : 0.f;
        w1t[t] = f2bf(v);
    }
    if (t < 4 * 8 * 64 * 8) {
        int j = t & 7, lane = (t >> 3) & 63, nf = (t >> 9) & 7, ks = t >> 12;
        int k = ks * 32 + (lane >> 4) * 8 + j;
        int d = nf * 16 + (lane & 15);
        w2t[t] = f2bf(bn1_g[k] * w2[k * 128 + d]);
    }
    if (t < 128) {
        float s1 = b1[t], s2 = b2[t];
        for (int ch = 0; ch < 200; ++ch) s1 += bn0_b[ch] * w1[ch * 128 + t];
        for (int k = 0; k < 128; ++k)   s2 += bn1_b[k] * w2[k * 128 + t];
        b1f[t] = s1; b2f[t] = s2;
    }
}

// ---------------------------------------------------------------------------
// cnn_mfma (round-12 verified): 4 waves/block, xfT[d][pix] bf16
// ---------------------------------------------------------------------------
__global__ __launch_bounds__(256) void cnn_mfma(
    const float* __restrict__ x, const short* __restrict__ w1t,
    const float* __restrict__ b1f, const short* __restrict__ w2t,
    const float* __restrict__ b2f, short* __restrict__ xfT)
{
    __shared__ __align__(16) short a2[4][4][4][64][8];   // 64 KB
    const int t = threadIdx.x;
    const int w = t >> 6, l = t & 63;
    const int q = l >> 4, li = l & 15;
    const int pix0 = blockIdx.x * 256 + w * 64;

    f32x4 acc[4][8];
#pragma unroll
    for (int nf = 0; nf < 8; ++nf) {
        float bv = b1f[nf * 16 + li];
#pragma unroll
        for (int mf = 0; mf < 4; ++mf) acc[mf][nf] = (f32x4){bv, bv, bv, bv};
    }

    for (int ks = 0; ks < 7; ++ks) {
        bf16x8 a[4];
        if (ks < 6 || q == 0) {
            int k0 = ks * 32 + q * 8;
#pragma unroll
            for (int mf = 0; mf < 4; ++mf) {
                const float* sp = &x[(size_t)(pix0 + mf * 16 + li) * 200 + k0];
                float4 u = *(const float4*)sp;
                float4 v = *(const float4*)(sp + 4);
                a[mf][0] = f2bf(u.x); a[mf][1] = f2bf(u.y);
                a[mf][2] = f2bf(u.z); a[mf][3] = f2bf(u.w);
                a[mf][4] = f2bf(v.x); a[mf][5] = f2bf(v.y);
                a[mf][6] = f2bf(v.z); a[mf][7] = f2bf(v.w);
            }
        } else {
#pragma unroll
            for (int mf = 0; mf < 4; ++mf)
#pragma unroll
                for (int j = 0; j < 8; ++j) a[mf][j] = 0;
        }
#pragma unroll
        for (int nf = 0; nf < 8; ++nf) {
            bf16x8 b = *(const bf16x8*)&w1t[((ks * 8 + nf) * 64 + l) * 8];
#pragma unroll
            for (int mf = 0; mf < 4; ++mf)
                acc[mf][nf] = __builtin_amdgcn_mfma_f32_16x16x32_bf16(a[mf], b, acc[mf][nf], 0, 0, 0);
        }
    }

#pragma unroll
    for (int mf = 0; mf < 4; ++mf)
#pragma unroll
        for (int nf = 0; nf < 8; ++nf)
#pragma unroll
            for (int j = 0; j < 4; ++j) {
                float v = lrelu(acc[mf][nf][j]);
                int row = mf * 16 + q * 4 + j;
                int col = nf * 16 + li;
                int ks2 = col >> 5;
                int lane2 = (row & 15) + (((col & 31) >> 3) << 4);
                a2[w][ks2][mf][lane2][col & 7] = f2bf(v);
            }
    __syncthreads();

    f32x4 acc2[4][8];
#pragma unroll
    for (int nf = 0; nf < 8; ++nf) {
        float bv = b2f[nf * 16 + li];
#pragma unroll
        for (int mf = 0; mf < 4; ++mf) acc2[mf][nf] = (f32x4){bv, bv, bv, bv};
    }
#pragma unroll
    for (int ks = 0; ks < 4; ++ks) {
        bf16x8 a[4];
#pragma unroll
        for (int mf = 0; mf < 4; ++mf)
            a[mf] = *(const bf16x8*)&a2[w][ks][mf][l][0];
#pragma unroll
        for (int nf = 0; nf < 8; ++nf) {
            bf16x8 b = *(const bf16x8*)&w2t[((ks * 8 + nf) * 64 + l) * 8];
#pragma unroll
            for (int mf = 0; mf < 4; ++mf)
                acc2[mf][nf] = __builtin_amdgcn_mfma_f32_16x16x32_bf16(a[mf], b, acc2[mf][nf], 0, 0, 0);
        }
    }

#pragma unroll
    for (int mf = 0; mf < 4; ++mf)
#pragma unroll
        for (int nf = 0; nf < 8; ++nf) {
            bf16x4 p;
#pragma unroll
            for (int j = 0; j < 4; ++j) p[j] = f2bf(lrelu(acc2[mf][nf][j]));
            int d2 = nf * 16 + li;
            int pix = pix0 + mf * 16 + q * 4;
            *(bf16x4*)&xfT[(size_t)d2 * HWP + pix] = p;
        }
}

// ---------------------------------------------------------------------------
// pool_mfma (round-17 verified)
// ---------------------------------------------------------------------------
__device__ __forceinline__ void pool_loadB(bf16x8 (&dst)[4], const short* __restrict__ xfT,
                                           int dcol0, int rbase)
{
#pragma unroll
    for (int nf = 0; nf < 4; ++nf)
        dst[nf] = *(const bf16x8*)&xfT[(size_t)(dcol0 + nf * 16) * HWP + rbase];
}

__device__ __forceinline__ void pool_stage(const float* __restrict__ Q, float* dst,
                                           int r0t, int n0blk, int wid, int l)
{
#pragma unroll
    for (int i = 0; i < 8; ++i) {
        int o = (i * 4 + wid) * 1024 + l * 16;     // byte offset in 32KB tile
        int row = o >> 9;                          // 512B per row (128 fp32)
        int wrd = (o & 511) >> 2;                  // word-in-row 0..127
        const float* src = Q + (size_t)(r0t + row) * NSP + n0blk
                             + (wrd ^ (((row >> 3) & 3) << 4));
        __builtin_amdgcn_global_load_lds(
            (const __attribute__((address_space(1))) unsigned int*)src,
            (__attribute__((address_space(3))) unsigned int*)(dst + (o >> 2)),
            16, 0, 0);
    }
}

__global__ __launch_bounds__(256, 2) void pool_mfma(
    const float* __restrict__ Q, const short* __restrict__ xfT,
    short* __restrict__ P_part, float* __restrict__ qs_part)
{
    __shared__ __align__(16) float qtile[2][8192];   // 2 x 32KB
    const int t = threadIdx.x;
    const int wid = t >> 6, l = t & 63;
    const int q = l >> 4, li = l & 15;
    const int nw = (wid >> 1) * 64;
    const int d0 = (wid & 1) * 64;
    // XCD swizzle: bid%8 = XCD (observed round-robin); give XCD k chunks 8k..8k+7
    const int bid   = blockIdx.x;          // 0..511
    const int xcd   = bid & 7;
    const int local = bid >> 3;            // 0..63
    const int n0blk = (local & 7) * 128;
    const int chunk = (local >> 3) | (xcd << 3);
    const int r0 = chunk * 1024;
    const int dcol0 = d0 + li;

    f32x4 acc[4][4];
    f32x4 accq[4];
#pragma unroll
    for (int mf = 0; mf < 4; ++mf) {
        accq[mf] = (f32x4){0.f, 0.f, 0.f, 0.f};
#pragma unroll
        for (int nf = 0; nf < 4; ++nf) acc[mf][nf] = (f32x4){0.f, 0.f, 0.f, 0.f};
    }
    bf16x8 bone;
    {
        short onev = (li == 0) ? (short)0x3F80 : (short)0;
#pragma unroll
        for (int j = 0; j < 8; ++j) bone[j] = onev;
    }

    // prologue: B(t0) + stage(t0)   [16 vmem ops in flight]
    bf16x8 bA[4], bB[4];
    pool_loadB(bA, xfT, dcol0, r0 + q * 8);
    pool_loadB(bB, xfT, dcol0, r0 + 32 + q * 8);
    pool_stage(Q, qtile[0], r0, n0blk, wid, l);

    for (int tile = 0; tile < 16; ++tile) {
        const int cur = tile & 1;
        raw_barrier();                               // prev compute's reads done
        bf16x8 nA[4], nB[4];
        if (tile < 15) {
            pool_loadB(nA, xfT, dcol0, r0 + (tile + 1) * 64 + q * 8);
            pool_loadB(nB, xfT, dcol0, r0 + (tile + 1) * 64 + 32 + q * 8);
            pool_stage(Q, qtile[cur ^ 1], r0 + (tile + 1) * 64, n0blk, wid, l);
            asm volatile("s_waitcnt vmcnt(16)" ::: "memory");   // tile-t ops done
        } else {
            asm volatile("s_waitcnt vmcnt(0)" ::: "memory");
        }
        raw_barrier();                               // stage(tile) visible
#pragma unroll
        for (int ks = 0; ks < 2; ++ks) {
            bf16x8 abf[4];
#pragma unroll
            for (int mf = 0; mf < 4; ++mf) {
#pragma unroll
                for (int j = 0; j < 8; ++j) {
                    int row = ks * 32 + q * 8 + j;           // (row>>3)&3 == q
                    int w2i = (nw + mf * 16 + li) ^ (q << 4);
                    abf[mf][j] = f2bf(qtile[cur][(row << 7) + w2i]);
                }
            }
#pragma unroll
            for (int mf = 0; mf < 4; ++mf) {
#pragma unroll
                for (int nf = 0; nf < 4; ++nf)
                    acc[mf][nf] = __builtin_amdgcn_mfma_f32_16x16x32_bf16(
                        abf[mf], (ks == 0) ? bA[nf] : bB[nf], acc[mf][nf], 0, 0, 0);
                if (d0 == 0)
                    accq[mf] = __builtin_amdgcn_mfma_f32_16x16x32_bf16(
                        abf[mf], bone, accq[mf], 0, 0, 0);
            }
        }
        if (tile < 15) {
#pragma unroll
            for (int nf = 0; nf < 4; ++nf) { bA[nf] = nA[nf]; bB[nf] = nB[nf]; }
        }
    }

#pragma unroll
    for (int mf = 0; mf < 4; ++mf)
#pragma unroll
        for (int nf = 0; nf < 4; ++nf)
#pragma unroll
            for (int j = 0; j < 4; ++j) {
                int n = n0blk + nw + mf * 16 + q * 4 + j;
                int d = d0 + nf * 16 + li;
                P_part[((size_t)chunk * NSP + n) * DCH + d] = f2bf(acc[mf][nf][j]);
            }
    if (d0 == 0 && li == 0)
#pragma unroll
        for (int mf = 0; mf < 4; ++mf)
#pragma unroll
            for (int j = 0; j < 4; ++j)
                qs_part[chunk * NSP + n0blk + nw + mf * 16 + q * 4 + j] = accq[mf][j];
}

// ---------------------------------------------------------------------------
// reduce_h0: bf16 partials, coalesced short8 loads; fp32 accumulate + divide
// ---------------------------------------------------------------------------
__global__ __launch_bounds__(256) void reduce_h0(
    const short* __restrict__ P_part, const float* __restrict__ qs_part,
    float* __restrict__ h)
{
    const int idx8 = blockIdx.x * 256 + threadIdx.x;   // 0..16383 (8-elem groups)
    const int n = idx8 >> 4;
    float s[8];
#pragma unroll
    for (int j = 0; j < 8; ++j) s[j] = 0.f;
    for (int k = 0; k < KC; ++k) {
        bf16x8 v = *(const bf16x8*)&P_part[(size_t)k * (NSP * DCH) + idx8 * 8];
#pragma unroll
        for (int j = 0; j < 8; ++j) s[j] += bf2f(v[j]);
    }
    float qs = 0.f;
    for (int k = 0; k < KC; ++k) qs += qs_part[k * NSP + n];
    float inv = 1.f / qs;
    f32x4 o0 = (f32x4){s[0] * inv, s[1] * inv, s[2] * inv, s[3] * inv};
    f32x4 o1 = (f32x4){s[4] * inv, s[5] * inv, s[6] * inv, s[7] * inv};
    ((f32x4*)h)[idx8 * 2]     = o0;
    ((f32x4*)h)[idx8 * 2 + 1] = o1;
}

// ---------------------------------------------------------------------------
// m1_k (verified; m1p now bf16): grid (64 r-tiles, 16 j-chunks of 64)
// ---------------------------------------------------------------------------
__global__ __launch_bounds__(256) void m1_k(
    const float* __restrict__ adj, const float* __restrict__ h,
    const float* __restrict__ dinv, const float* __restrict__ gg,
    const float* __restrict__ gb, short* __restrict__ m1p)
{
    __shared__ float adjL[16][64];
    __shared__ float hbL[64][128];
    const int r0 = blockIdx.x * 16;
    const int jc = blockIdx.y;
    const int j0 = jc * 64;
    const int t = threadIdx.x;
    const int d = t & 127, ph = t >> 7;

    for (int i = t; i < 16 * 64; i += 256) {
        int row = i >> 6, col = i & 63;
        adjL[row][col] = adj[(size_t)(r0 + row) * NSP + j0 + col];
    }
    for (int i = t; i < 64 * 128; i += 256) {
        int jr = i >> 7, dd = i & 127;
        int j = j0 + jr;
        hbL[jr][dd] = dinv[j] * (gg[dd] * h[(size_t)j * DCH + dd] + gb[dd]);
    }
    __syncthreads();

    float acc[8];
#pragma unroll
    for (int pp = 0; pp < 8; ++pp) acc[pp] = 0.f;
    for (int jj = 0; jj < 64; ++jj) {
        float hv = hbL[jj][d];
#pragma unroll
        for (int pp = 0; pp < 8; ++pp)
            acc[pp] += adjL[ph * 8 + pp][jj] * hv;
    }
#pragma unroll
    for (int pp = 0; pp < 8; ++pp)
        m1p[(size_t)jc * (NSP * DCH) + (size_t)(r0 + ph * 8 + pp) * DCH + d] = f2bf(acc[pp]);
}

// ---------------------------------------------------------------------------
// gcnw_k (verified; m1p now bf16) + fused htb write
// ---------------------------------------------------------------------------
__global__ __launch_bounds__(256) void gcnw_k(
    const short* __restrict__ m1p, const float* __restrict__ h,
    const float* __restrict__ dinv, const float* __restrict__ gg,
    const float* __restrict__ gb, const float* __restrict__ W,
    const float* __restrict__ bias, float* __restrict__ hout,
    short* __restrict__ htb)
{
    __shared__ float ms[16 * 128];
    __shared__ float WL[64 * 128];
    const int r0 = blockIdx.x * 16;
    const int t = threadIdx.x;
    for (int i = t; i < 2048; i += 256) {
        int r = r0 + (i >> 7), dd = i & 127;
        float hbr = dinv[r] * (gg[dd] * h[(size_t)r * DCH + dd] + gb[dd]);
        float s = hbr;
#pragma unroll
        for (int kc = 0; kc < JC; ++kc)
            s += bf2f(m1p[(size_t)kc * (NSP * DCH) + (size_t)r0 * DCH + i]);
        ms[i] = dinv[r] * s;
    }
    const int e = t & 127, ph = t >> 7;
    float acc[8];
#pragma unroll
    for (int pp = 0; pp < 8; ++pp) acc[pp] = bias[e];
    for (int sub = 0; sub < 2; ++sub) {
        __syncthreads();
        for (int i = t; i < 64 * 128; i += 256)
            WL[i] = W[(size_t)sub * 64 * 128 + i];
        __syncthreads();
        for (int dd = 0; dd < 64; ++dd) {
            float wv = WL[dd * 128 + e];
#pragma unroll
            for (int pp = 0; pp < 8; ++pp)
                acc[pp] += ms[(ph * 8 + pp) * 128 + sub * 64 + dd] * wv;
        }
    }
#pragma unroll
    for (int pp = 0; pp < 8; ++pp) {
        int r = r0 + ph * 8 + pp;
        float v = lrelu(acc[pp]);
        hout[(size_t)r * DCH + e] = v;
        int lane = (((r >> 3) & 3) << 4) + (e & 15);
        htb[(((r >> 5) * 8 + (e >> 4)) * 64 + lane) * 8 + (r & 7)] = f2bf(v);
    }
}

// ---------------------------------------------------------------------------
// out_mfma (round-17 verified)
// ---------------------------------------------------------------------------
__device__ __forceinline__ void out_loadB(bf16x8 (&dst)[4], const short* __restrict__ htb,
                                          int ks, int nfbase, int l)
{
#pragma unroll
    for (int nf = 0; nf < 4; ++nf)
        dst[nf] = *(const bf16x8*)&htb[((ks * 8 + nfbase + nf) * 64 + l) * 8];
}

__device__ __forceinline__ void stage_q(const float* __restrict__ Q, float* dst,
                                        int r0, int kbase, int wid, int l)
{
#pragma unroll
    for (int i = 0; i < 8; ++i) {
        int o = (i * 4 + wid) * 1024 + l * 16;      // byte offset in 32KB tile
        int row = o >> 8;                           // 256B per row (64 fp32)
        int bin = o & 255;                          // 16B-aligned
        const float* src = Q + (size_t)(r0 + row) * NSP + kbase
                             + ((bin ^ ((row & 7) << 5)) >> 2);
        __builtin_amdgcn_global_load_lds(
            (const __attribute__((address_space(1))) unsigned int*)src,
            (__attribute__((address_space(3))) unsigned int*)(dst + (o >> 2)),
            16, 0, 0);
    }
}

__global__ __launch_bounds__(256, 2) void out_mfma(
    const float* __restrict__ Q, const short* __restrict__ htb,
    float* __restrict__ out)
{
    __shared__ __align__(16) float qs[2][8192];     // 2 x 32KB
    const int t = threadIdx.x;
    const int wid = t >> 6, l = t & 63;
    const int q = l >> 4, li = l & 15;
    const int r0 = blockIdx.x * 128;
    const int rw = (wid >> 1) * 64;
    const int d0 = (wid & 1) * 64;
    const int nfb = d0 >> 4;

    f32x4 acc[4][4];
#pragma unroll
    for (int mf = 0; mf < 4; ++mf)
#pragma unroll
        for (int nf = 0; nf < 4; ++nf) acc[mf][nf] = (f32x4){0.f, 0.f, 0.f, 0.f};

    bf16x8 bA[4], bB[4];
    out_loadB(bA, htb, 0, nfb, l);
    out_loadB(bB, htb, 1, nfb, l);
    stage_q(Q, qs[0], r0, 0, wid, l);

    for (int tile = 0; tile < 16; ++tile) {
        const int cur = tile & 1;
        raw_barrier();                               // prev compute's reads done
        bf16x8 nA[4], nB[4];
        if (tile < 15) {
            out_loadB(nA, htb, (tile + 1) * 2,     nfb, l);
            out_loadB(nB, htb, (tile + 1) * 2 + 1, nfb, l);
            stage_q(Q, qs[cur ^ 1], r0, (tile + 1) * 64, wid, l);
            asm volatile("s_waitcnt vmcnt(16)" ::: "memory");
        } else {
            asm volatile("s_waitcnt vmcnt(0)" ::: "memory");
        }
        raw_barrier();                               // stage(tile) visible
#pragma unroll
        for (int ks = 0; ks < 2; ++ks) {
            bf16x8 abf[4];
#pragma unroll
            for (int mf = 0; mf < 4; ++mf) {
                int rl = rw + mf * 16 + li;
                int koff = (ks * 32 + q * 8) << 2;
                const float* p = &qs[cur][(rl << 6) + ((koff ^ ((rl & 7) << 5)) >> 2)];
                float4 u = *(const float4*)p;
                float4 v = *(const float4*)(p + 4);
                abf[mf][0] = f2bf(u.x); abf[mf][1] = f2bf(u.y);
                abf[mf][2] = f2bf(u.z); abf[mf][3] = f2bf(u.w);
                abf[mf][4] = f2bf(v.x); abf[mf][5] = f2bf(v.y);
                abf[mf][6] = f2bf(v.z); abf[mf][7] = f2bf(v.w);
            }
            if (ks == 0) {
#pragma unroll
                for (int mf = 0; mf < 4; ++mf)
#pragma unroll
                    for (int nf = 0; nf < 4; ++nf)
                        acc[mf][nf] = __builtin_amdgcn_mfma_f32_16x16x32_bf16(abf[mf], bA[nf], acc[mf][nf], 0, 0, 0);
            } else {
#pragma unroll
                for (int mf = 0; mf < 4; ++mf)
#pragma unroll
                    for (int nf = 0; nf < 4; ++nf)
                        acc[mf][nf] = __builtin_amdgcn_mfma_f32_16x16x32_bf16(abf[mf], bB[nf], acc[mf][nf], 0, 0, 0);
            }
        }
        if (tile < 15) {
#pragma unroll
            for (int nf = 0; nf < 4; ++nf) { bA[nf] = nA[nf]; bB[nf] = nB[nf]; }
        }
    }

#pragma unroll
    for (int mf = 0; mf < 4; ++mf)
#pragma unroll
        for (int nf = 0; nf < 4; ++nf)
#pragma unroll
            for (int j = 0; j < 4; ++j)
                out[(size_t)(r0 + rw + mf * 16 + q * 4 + j) * DCH + d0 + nf * 16 + li] = acc[mf][nf][j];
}

// ---------------------------------------------------------------------------
extern "C" void kernel_launch(void* const* d_in, const int* in_sizes, int n_in,
                              void* d_out, int out_size, void* d_ws, size_t ws_size,
                              hipStream_t stream)
{
    const float* x      = (const float*)d_in[0];
    const float* Q      = (const float*)d_in[1];
    const float* adj    = (const float*)d_in[2];
    const float* bn0_g  = (const float*)d_in[3];
    const float* bn0_b  = (const float*)d_in[4];
    const float* w1     = (const float*)d_in[5];
    const float* b1     = (const float*)d_in[6];
    const float* bn1_g  = (const float*)d_in[7];
    const float* bn1_b  = (const float*)d_in[8];
    const float* w2     = (const float*)d_in[9];
    const float* b2     = (const float*)d_in[10];
    const float* gbn_g  = (const float*)d_in[11];
    const float* gbn_b  = (const float*)d_in[12];
    const float* gcn_w  = (const float*)d_in[13];
    const float* gcn_b  = (const float*)d_in[14];

    float* out = (float*)d_out;
    float* ws  = (float*)d_ws;

    // workspace layout (float units; P_part region reused as bf16 buffer)
    float* P_reg   = ws;                                   // 8,388,608 f region
    float* qs_part = P_reg + (size_t)KC * NSP * DCH;       // 65,536
    float* hA      = qs_part + (size_t)KC * NSP;           // 131,072
    float* hB      = hA + NSP * DCH;                       // 131,072
    float* dinvb   = hB + NSP * DCH;                       // 1,024
    short* htb     = (short*)(dinvb + NSP);                // 131,072 bf16
    short* w1t     = (short*)((float*)htb + 65536);        // 28,672 bf16
    short* w2t     = (short*)((float*)w1t + 14336);        // 16,384 bf16
    float* b1f     = (float*)w2t + 8192;                   // 128
    float* b2f     = b1f + 128;                            // 128
    short* P_part  = (short*)P_reg;                        // KC*NSP*DCH bf16
    // GCN partials overlay P_reg (dead after reduce_h0): JC*NSP*DCH bf16
    short* m1p     = (short*)P_reg;
    // xfT lives in the (currently dead) d_out buffer
    short* xfT     = (short*)d_out;

    prep_w<<<112 + NSP, 256, 0, stream>>>(w1, b1, bn0_g, bn0_b, w2, b2,
                                          bn1_g, bn1_b, adj,
                                          w1t, w2t, b1f, b2f, dinvb);
    cnn_mfma<<<HWP / 256, 256, 0, stream>>>(x, w1t, b1f, w2t, b2f, xfT);
    pool_mfma<<<(NSP / 128) * KC, 256, 0, stream>>>(Q, xfT, P_part, qs_part);
    reduce_h0<<<(NSP * DCH / 8) / 256, 256, 0, stream>>>(P_part, qs_part, hA);

    const float* hcur = hA;
    float* hnext = hB;
    for (int i = 0; i < 3; ++i) {
        m1_k<<<dim3(NSP / 16, JC), 256, 0, stream>>>(adj, hcur, dinvb,
                                                     gbn_g + i * DCH, gbn_b + i * DCH, m1p);
        gcnw_k<<<NSP / 16, 256, 0, stream>>>(m1p, hcur, dinvb,
                                             gbn_g + i * DCH, gbn_b + i * DCH,
                                             gcn_w + (size_t)i * DCH * DCH,
                                             gcn_b + i * DCH, hnext, htb);
        const float* tmp = hcur;
        hcur = hnext;
        hnext = (float*)tmp;
    }

    out_mfma<<<HWP / 128, 256, 0, stream>>>(Q, htb, out);
}